// Round 17
// baseline (467.657 us; speedup 1.0000x reference)
//
#include <hip/hip_runtime.h>
#include <hip/hip_bf16.h>
#include <hip/hip_fp8.h>
#include <stdint.h>

typedef unsigned char  u8;
typedef unsigned short u16;
typedef unsigned int   u32;
typedef unsigned long long u64;
typedef __attribute__((ext_vector_type(4))) float f32x4;
typedef __attribute__((ext_vector_type(4))) unsigned int u32x4;
typedef __attribute__((ext_vector_type(8))) short s16x8;

#define NEG_INF (-1e9f)

__device__ __forceinline__ u16 f2bf(float f) {
  __hip_bfloat16 h = __float2bfloat16(f);
  return __builtin_bit_cast(u16, h);
}

__device__ __forceinline__ u8 f2fp8(float f) {
  __hip_fp8_e4m3 h(f);
  return (u8)h.__x;
}

// HW packed fp32->fp8 conversion (OCP on gfx950); safe fallback if absent.
#if defined(__has_builtin)
#if __has_builtin(__builtin_amdgcn_cvt_pk_fp8_f32)
#define HAVE_PK8 1
#endif
#endif

__device__ __forceinline__ u32 pk4_fp8(float a, float b, float c, float d) {
#ifdef HAVE_PK8
  int r = __builtin_amdgcn_cvt_pk_fp8_f32(a, b, 0, false);
  r = __builtin_amdgcn_cvt_pk_fp8_f32(c, d, r, true);
  return (u32)r;
#else
  return (u32)f2fp8(a) | ((u32)f2fp8(b) << 8) | ((u32)f2fp8(c) << 16) |
         ((u32)f2fp8(d) << 24);
#endif
}

__device__ __forceinline__ f32x4 mfma16(s16x8 a, s16x8 b, f32x4 c) {
  return __builtin_amdgcn_mfma_f32_16x16x32_bf16(a, b, c, 0, 0, 0);
}

__device__ __forceinline__ f32x4 mfma8(long a, long b, f32x4 c) {
  return __builtin_amdgcn_mfma_f32_16x16x32_fp8_fp8(a, b, c, 0, 0, 0);
}

// async global->LDS, 16 B per lane; LDS dest is wave-uniform base + lane*16
#define GLOAD16(g, l)                                                        \
  __builtin_amdgcn_global_load_lds(                                          \
      (const __attribute__((address_space(1))) unsigned int*)(g),            \
      (__attribute__((address_space(3))) unsigned int*)(l), 16, 0, 0)
// width-4 variant; LDS dest = base + lane*4
#define GLOAD4(g, l)                                                         \
  __builtin_amdgcn_global_load_lds(                                          \
      (const __attribute__((address_space(1))) unsigned int*)(g),            \
      (__attribute__((address_space(3))) unsigned int*)(l), 4, 0, 0)

#define WAITV(n) asm volatile("s_waitcnt vmcnt(" #n ")" ::: "memory")
#define WAITLGKM asm volatile("s_waitcnt lgkmcnt(0)" ::: "memory")
#define SBAR __builtin_amdgcn_sched_barrier(0)
#define HBAR __builtin_amdgcn_s_barrier()

// ------------------------------------------- mask prep (fused dtype detect)
__global__ __launch_bounds__(256) void maskprep_kernel(const void* __restrict__ mraw,
                                                       unsigned char* __restrict__ mb) {
  __shared__ int anyS;
  const int tid = threadIdx.x;
  int loc = 0;
  {
    u32 v = ((const u32*)mraw)[tid];
    if (v & 0xFFFFFF00u) loc = 1;  // int32 0/1 never sets high bytes
  }
  if (tid == 0) anyS = 0;
  __syncthreads();
  if (loc) atomicOr(&anyS, 1);
  __syncthreads();
  const int is1byte = anyS;

  long long idx = (long long)blockIdx.x * 256 + tid;  // B*T*64 = 2097152
  long long bt = idx >> 6;
  int ch = (int)(idx & 63);
  unsigned char byte = 0;
  if (is1byte) {
    u64 v = *(const u64*)((const unsigned char*)mraw + bt * 512 + ch * 8);
#pragma unroll
    for (int i = 0; i < 8; i++)
      if ((v >> (8 * i)) & 0xFFull) byte |= (unsigned char)(1 << i);
  } else {
    const int* p = (const int*)mraw + bt * 512 + ch * 8;
#pragma unroll
    for (int i = 0; i < 8; i++)
      if (p[i]) byte |= (unsigned char)(1 << i);
  }
  mb[idx] = byte;
}

// ---------------------------------------------------------------- weight prep
__global__ void tcvt8_kernel(const float* __restrict__ in, int ld_in, int kreal,
                             int CO, u8* __restrict__ outp) {
  int i = blockIdx.x;
  for (int j = threadIdx.x; j < CO; j += 256) {
    float v = (j < kreal) ? in[(long long)j * ld_in + i] * 16.0f : 0.0f;
    outp[(long long)i * CO + j] = f2fp8(v);
  }
}

__global__ void slice_cvt_kernel(const float* __restrict__ in, u16* __restrict__ outp) {
  long long idx = (long long)blockIdx.x * 256 + threadIdx.x;  // 262144
  long long dd = idx >> 9;
  int hh = (int)(idx & 511);
  outp[idx] = f2bf(in[dd * 1536 + 1024 + hh]);
}

__global__ void cvt_bf_kernel(const float* __restrict__ in, u16* __restrict__ outp) {
  long long idx = (long long)blockIdx.x * 256 + threadIdx.x;
  outp[idx] = f2bf(in[idx]);
}

// ---------------- emb fp32 -> fp8 + partial mean (fused)
__global__ __launch_bounds__(256) void cvt_pmean_kernel(const float* __restrict__ emb,
                                                        u8* __restrict__ e8,
                                                        float* __restrict__ pmean) {
  const int bq = blockIdx.x >> 2, nq = blockIdx.x & 3;
  const int tid = threadIdx.x;
  const int ro = tid >> 7;
  const int c4 = (tid & 127) << 2;
  const long long base = ((long long)bq * 512 + nq * 128) * 512;
  float s[4] = {0.f, 0.f, 0.f, 0.f};
  for (int n = ro; n < 128; n += 2) {
    f32x4 v = *(const f32x4*)&emb[base + (long long)n * 512 + c4];
#pragma unroll
    for (int i = 0; i < 4; i++) s[i] += v[i];
    *(u32*)&e8[base + (long long)n * 512 + c4] = pk4_fp8(v[0], v[1], v[2], v[3]);
  }
  __shared__ float ls[2][512];
#pragma unroll
  for (int i = 0; i < 4; i++) ls[ro][c4 + i] = s[i];
  __syncthreads();
  float* dst = pmean + (long long)blockIdx.x * 512;
  dst[tid] = ls[0][tid] + ls[1][tid];
  dst[tid + 256] = ls[0][tid + 256] + ls[1][tid + 256];
}

__global__ __launch_bounds__(256) void fixedctx_kernel(const float* __restrict__ pmean,
                                                       const float* __restrict__ Wc,
                                                       float* __restrict__ fixedc) {
  __shared__ float mf[512];
  int b = blockIdx.x;
  const float* p = pmean + (long long)b * 4 * 512;
  for (int d = threadIdx.x; d < 512; d += 256)
    mf[d] = (p[d] + p[512 + d] + p[1024 + d] + p[1536 + d]) * (1.0f / 512.0f);
  __syncthreads();
  for (int h = threadIdx.x; h < 512; h += 256) {
    float s = 0.f;
    for (int d = 0; d < 512; ++d) s += mf[d] * Wc[(long long)d * 512 + h];
    fixedc[(long long)b * 512 + h] = s;
  }
}

// -------------------------------- next-node features, fp8 (gather from e8, ld 576)
__global__ __launch_bounds__(256) void build_nextn8_kernel(
    const u8* __restrict__ e8, const int* __restrict__ cur,
    const float* __restrict__ ucap, const float* __restrict__ ubat,
    const float* __restrict__ ctim, u8* __restrict__ outp) {
  const long long rowm = (long long)blockIdx.x * 4 + (threadIdx.x >> 6);
  const int lane = threadIdx.x & 63;
  const int b = (int)(rowm >> 7);
  const int node = cur[rowm];
  const u8* src = e8 + ((long long)b * 512 + node) * 512;
  u8* dst = outp + rowm * 576;
  *(u64*)&dst[lane * 8] = *(const u64*)&src[lane * 8];
  if (lane < 8) {
    u64 v = 0;
    if (lane == 0) {
      v = (u64)f2fp8(1.0f - ucap[rowm]) | ((u64)f2fp8(1.0f - ubat[rowm]) << 8) |
          ((u64)f2fp8(ctim[rowm]) << 16);
    }
    *(u64*)&dst[512 + lane * 8] = v;
  }
}

// =============================================================================
// KV projection GEMM (fp8) — 3-deep pipeline (vmcnt(6)), 3 x 24 KB buffers.
// Epilogue transpose scratch reuses the just-consumed tile's buffer (stage of
// tile u*8+10 is deferred to after the epilogue; wave-private slices make the
// reuse safe). LDS total 72 KB -> 2 blocks/CU maintained.
// =============================================================================
__global__ __launch_bounds__(512, 4) void gemm_kv8_kernel(
    const u8* __restrict__ A8, const u8* __restrict__ Bw8,
    u8* __restrict__ K8, u8* __restrict__ V8) {
  __shared__ __align__(16) char lds[73728];  // 3 x (A 16K + B 8K)
  const int tid = threadIdx.x;
  const int lane = tid & 63;
  const int wid = tid >> 6;
  const int wr = wid >> 1, wc = wid & 1;  // 4M x 2N
  const int fr = lane & 15;
  const int fq = lane >> 4;

  const int p = blockIdx.x;   // 512 blocks, 64/XCD
  const int x = p & 7;
  const int i = p >> 3;       // 0..63
  const int ntile = i & 7;    // N = 1024 / 128
  const int mgrp = i >> 3;    // 0..7
  const long long nrow0 = (long long)ntile * 128;

  const int srow = tid >> 2;  // 0..127 staging row
  const int sc = tid & 3;     // 16B chunk

#define MROW(tt2) (((long long)x * 64 + mgrp * 8 + ((tt2) >> 3)) * 256)
#define KOF(tt2) (((tt2) & 7) * 64)

#define STAGEA(dd, tt2)                                                       \
  {                                                                           \
    _Pragma("unroll") for (int g_ = 0; g_ < 2; g_++) {                        \
      const int r_ = g_ * 128 + srow;                                         \
      GLOAD16(A8 + (MROW(tt2) + r_) * 512ll + KOF(tt2) +                      \
                  ((sc ^ ((r_ >> 1) & 3)) << 4),                              \
              lds + (dd) * 24576 + g_ * 8192 + wid * 1024);                   \
    }                                                                         \
  }
#define STAGEB(dd, tt2)                                                       \
  {                                                                           \
    GLOAD16(Bw8 + (nrow0 + srow) * 512ll + KOF(tt2) +                         \
                ((sc ^ ((srow >> 1) & 3)) << 4),                              \
            lds + (dd) * 24576 + 16384 + wid * 1024);                         \
  }

#define READ_A(dst, mb)                                                       \
  _Pragma("unroll") for (int ks = 0; ks < 2; ks++) {                          \
    const int r_ = wr * 64 + (mb) * 16 + fr;                                  \
    dst[ks] = *(const long*)(ab + r_ * 64 + (((ks * 4 + fq) ^ (r_ & 6)) << 3)); \
  }
#define MFMA_PH(src, mb)                                                      \
  _Pragma("unroll") for (int nb = 0; nb < 4; nb++)                            \
  _Pragma("unroll") for (int ks = 0; ks < 2; ks++)                            \
    acc[mb][nb] = mfma8(src[ks], bfrag[nb][ks], acc[mb][nb]);

  // prologue: tiles 0, 1, 2 into buffers 0, 1, 2
  STAGEB(0, 0); STAGEA(0, 0);
  STAGEB(1, 1); STAGEA(1, 1);
  STAGEB(2, 2); STAGEA(2, 2);

  f32x4 acc[4][4];
  const int hh = (ntile * 2 + wc) & 7;

#pragma unroll 1
  for (int u = 0; u < 8; u++) {
#pragma unroll
    for (int ii = 0; ii < 4; ii++)
#pragma unroll
      for (int jj = 0; jj < 4; jj++) acc[ii][jj] = (f32x4){0.f, 0.f, 0.f, 0.f};

#pragma unroll 1
    for (int t8 = 0; t8 < 8; t8++) {
      const int tt = u * 8 + t8;
      const int d = tt % 3;
      if (tt == 63) { WAITV(0); }
      else if (tt == 62) { WAITV(3); }
      else { WAITV(6); }
      HBAR; SBAR;

      const char* ab = lds + d * 24576;
      const char* bb = lds + d * 24576 + 16384;

      long bfrag[4][2];
#pragma unroll
      for (int nb = 0; nb < 4; nb++)
#pragma unroll
        for (int ks = 0; ks < 2; ks++) {
          const int brow = wc * 64 + nb * 16 + fr;
          bfrag[nb][ks] =
              *(const long*)(bb + brow * 64 + (((ks * 4 + fq) ^ (brow & 6)) << 3));
        }
      long afA[2], afB[2];
      READ_A(afA, 0);
      WAITLGKM; SBAR;
      READ_A(afB, 1);
      __builtin_amdgcn_s_setprio(1);
      MFMA_PH(afA, 0);
      __builtin_amdgcn_s_setprio(0);
      WAITLGKM; SBAR;
      READ_A(afA, 2);
      __builtin_amdgcn_s_setprio(1);
      MFMA_PH(afB, 1);
      __builtin_amdgcn_s_setprio(0);
      WAITLGKM; SBAR;
      READ_A(afB, 3);
      __builtin_amdgcn_s_setprio(1);
      MFMA_PH(afA, 2);
      __builtin_amdgcn_s_setprio(0);
      WAITLGKM; SBAR;
      HBAR;  // all waves done reading buffer d (tile tt)
      // stage tile tt+3 into the SAME buffer d ((tt+3)%3 == tt%3);
      // deferred to after the epilogue when t8 == 7 (buffer doubles as scratch)
      if (t8 < 7 && tt + 3 < 64) { STAGEB(d, tt + 3); STAGEA(d, tt + 3); }
      __builtin_amdgcn_s_setprio(1);
      MFMA_PH(afB, 3);
      __builtin_amdgcn_s_setprio(0);
    }

    // ---- coalesced epilogue via per-wave LDS transpose tile ----
    // scratch = the buffer of tile u*8+7 (just consumed, not yet restaged);
    // each wave uses only its private 1 KB slice.
    char* tile = lds + ((u * 8 + 7) % 3) * 24576 + wid * 1024;
    const long long mrow0 = MROW(u * 8);
    const int bbx = (int)(mrow0 >> 9);
    const int nodeb = (int)(mrow0 & 511);
    const long long bhoff = ((long long)(bbx * 8 + hh)) << 15;

    if (ntile < 4) {
      // K path: tile logical [16 node][64 kk] bytes, dword-XOR swizzled
#pragma unroll
      for (int mb = 0; mb < 4; mb++) {
#pragma unroll
        for (int nb = 0; nb < 4; nb++) {
          const u32 pw = pk4_fp8(acc[mb][nb][0] * 0.0625f, acc[mb][nb][1] * 0.0625f,
                                 acc[mb][nb][2] * 0.0625f, acc[mb][nb][3] * 0.0625f);
          const int colhi = (nb * 16 + (fr & ~3));
          const int collo = fr & 3;
#pragma unroll
          for (int q = 0; q < 4; q++) {
            const int row = fq * 4 + q;
            tile[row * 64 + (colhi ^ ((row & 15) << 2)) + collo] = (u8)(pw >> (8 * q));
          }
        }
        WAITLGKM; SBAR;
        const int row = lane >> 2;
        u32x4 val;
#pragma unroll
        for (int j = 0; j < 4; j++) {
          const int dw = ((lane & 3) * 4 + j) << 2;
          val[j] = *(const u32*)(tile + row * 64 + (dw ^ ((row & 15) << 2)));
        }
        WAITLGKM; SBAR;
        u8* dst = K8 + bhoff + (long long)(nodeb + wr * 64 + mb * 16) * 64;
        *(u32x4*)(dst + lane * 16) = val;
      }
    } else {
      // V path: tile [64 kk][16 node] bytes; u32 writes along node.
#pragma unroll
      for (int mb = 0; mb < 4; mb++) {
#pragma unroll
        for (int nb = 0; nb < 4; nb++) {
          const u32 pw = pk4_fp8(acc[mb][nb][0] * 0.0625f, acc[mb][nb][1] * 0.0625f,
                                 acc[mb][nb][2] * 0.0625f, acc[mb][nb][3] * 0.0625f);
          *(u32*)(tile + (nb * 16 + fr) * 16 + fq * 4) = pw;
        }
        WAITLGKM; SBAR;
        u32x4 val = *(const u32x4*)(tile + lane * 16);  // kk = lane
        WAITLGKM; SBAR;
        const int ngrp = (nodeb + wr * 64 + mb * 16) >> 4;
        u8* dst = V8 + bhoff + (long long)ngrp * 1024;
        *(u32x4*)(dst + lane * 16) = val;
      }
    }

    // deferred stage of tile u*8+10 into the scratch buffer (wave-private
    // ordering: this wave's scratch reads completed at the last WAITLGKM)
    {
      const int tnext = u * 8 + 10;
      if (tnext < 64) {
        const int d2 = tnext % 3;
        STAGEB(d2, tnext); STAGEA(d2, tnext);
      }
    }
  }
#undef STAGEA
#undef STAGEB
#undef READ_A
#undef MFMA_PH
#undef MROW
#undef KOF
}

// =============================================================================
// gemm8: generic fp8 GEMM (unchanged)
// MODE 0 (query): out = fp8( (acc/16 + fixedc[b][col]) * 2 )   [q8 = 2q]
// MODE 1 (tmp):   out = fp8( acc / 32 )                        [tmp8 = 8*true]
// =============================================================================
template <int MODE>
__global__ __launch_bounds__(512, 4) void gemm8_kernel(
    const u8* __restrict__ A8, const u8* __restrict__ B8,
    int ldA, int ldB, int NT,
    u8* __restrict__ out0, const float* __restrict__ aux) {
  __shared__ __align__(16) char lds[49152];
  const int tid = threadIdx.x;
  const int lane = tid & 63;
  const int wid = tid >> 6;
  const int wr = wid >> 1, wc = wid & 1;
  const int fr = lane & 15;
  const int fq = lane >> 4;

  const int p = blockIdx.x;          // 512
  const int wk = (p & 7) * 64 + (p >> 3);
  const int mtile = wk >> 2;
  const int ntile = wk & 3;
  const long long mrow0 = (long long)mtile * 256;
  const long long nrow0 = (long long)ntile * 128;

  const int srow = tid >> 2;
  const int sc = tid & 3;

#define STAGEA8(dd, k0)                                                       \
  {                                                                           \
    _Pragma("unroll") for (int g_ = 0; g_ < 2; g_++) {                        \
      const int r_ = g_ * 128 + srow;                                         \
      GLOAD16(A8 + (mrow0 + r_) * (long long)ldA + (k0) +                     \
                  ((sc ^ ((r_ >> 1) & 3)) << 4),                              \
              lds + (dd) * 24576 + g_ * 8192 + wid * 1024);                   \
    }                                                                         \
  }
#define STAGEB8(dd, k0)                                                       \
  {                                                                           \
    GLOAD16(B8 + (nrow0 + srow) * (long long)ldB + (k0) +                     \
                ((sc ^ ((srow >> 1) & 3)) << 4),                              \
            lds + (dd) * 24576 + 16384 + wid * 1024);                         \
  }
#define READ_A8(dst, mb)                                                      \
  _Pragma("unroll") for (int ks = 0; ks < 2; ks++) {                          \
    const int r_ = wr * 64 + (mb) * 16 + fr;                                  \
    dst[ks] = *(const long*)(ab + r_ * 64 + (((ks * 4 + fq) ^ (r_ & 6)) << 3)); \
  }
#define MFMA_PH8(src, mb)                                                     \
  _Pragma("unroll") for (int nb = 0; nb < 4; nb++)                            \
  _Pragma("unroll") for (int ks = 0; ks < 2; ks++)                            \
    acc[mb][nb] = mfma8(src[ks], bfrag[nb][ks], acc[mb][nb]);

  f32x4 acc[4][4];
#pragma unroll
  for (int ii = 0; ii < 4; ii++)
#pragma unroll
    for (int jj = 0; jj < 4; jj++) acc[ii][jj] = (f32x4){0.f, 0.f, 0.f, 0.f};

  STAGEB8(0, 0); STAGEA8(0, 0);
  STAGEB8(1, 64); STAGEA8(1, 64);

#pragma unroll 1
  for (int t = 0; t < NT; t++) {
    const int d = t & 1;
    if (t == NT - 1) { WAITV(0); } else { WAITV(3); }
    HBAR; SBAR;

    const char* ab = lds + d * 24576;
    const char* bb = lds + d * 24576 + 16384;

    long bfrag[4][2];
#pragma unroll
    for (int nb = 0; nb < 4; nb++)
#pragma unroll
      for (int ks = 0; ks < 2; ks++) {
        const int brow = wc * 64 + nb * 16 + fr;
        bfrag[nb][ks] =
            *(const long*)(bb + brow * 64 + (((ks * 4 + fq) ^ (brow & 6)) << 3));
      }
    long afA[2], afB[2];
    READ_A8(afA, 0);
    WAITLGKM; SBAR;
    READ_A8(afB, 1);
    __builtin_amdgcn_s_setprio(1);
    MFMA_PH8(afA, 0);
    __builtin_amdgcn_s_setprio(0);
    WAITLGKM; SBAR;
    READ_A8(afA, 2);
    __builtin_amdgcn_s_setprio(1);
    MFMA_PH8(afB, 1);
    __builtin_amdgcn_s_setprio(0);
    WAITLGKM; SBAR;
    READ_A8(afB, 3);
    __builtin_amdgcn_s_setprio(1);
    MFMA_PH8(afA, 2);
    __builtin_amdgcn_s_setprio(0);
    WAITLGKM; SBAR;
    HBAR;
    if (t + 2 < NT) { STAGEB8(d, (t + 2) * 64); STAGEA8(d, (t + 2) * 64); }
    __builtin_amdgcn_s_setprio(1);
    MFMA_PH8(afB, 3);
    __builtin_amdgcn_s_setprio(0);
  }
#undef STAGEA8
#undef STAGEB8
#undef READ_A8
#undef MFMA_PH8

  const int colbase = (int)(ntile * 128) + wc * 64;
#pragma unroll
  for (int mb = 0; mb < 4; mb++) {
    const long long row0 = mrow0 + wr * 64 + mb * 16 + fq * 4;
#pragma unroll
    for (int nb = 0; nb < 4; nb++) {
      const int col = colbase + nb * 16 + fr;
      u32 pw;
      if (MODE == 0) {
        float v0 = acc[mb][nb][0] * 0.0625f + aux[((row0 + 0) >> 7) * 512 + col];
        float v1 = acc[mb][nb][1] * 0.0625f + aux[((row0 + 1) >> 7) * 512 + col];
        float v2 = acc[mb][nb][2] * 0.0625f + aux[((row0 + 2) >> 7) * 512 + col];
        float v3 = acc[mb][nb][3] * 0.0625f + aux[((row0 + 3) >> 7) * 512 + col];
        pw = pk4_fp8(v0 * 2.0f, v1 * 2.0f, v2 * 2.0f, v3 * 2.0f);
      } else {
        pw = pk4_fp8(acc[mb][nb][0] * 0.03125f, acc[mb][nb][1] * 0.03125f,
                     acc[mb][nb][2] * 0.03125f, acc[mb][nb][3] * 0.03125f);
      }
#pragma unroll
      for (int q = 0; q < 4; q++)
        out0[(row0 + q) * 512 + col] = (u8)(pw >> (8 * q));
    }
  }
}

// =============================================================================
// gemm_lsm8 (unchanged)
// =============================================================================
__global__ __launch_bounds__(512, 4) void gemm_lsm8_kernel(
    const u8* __restrict__ e8, const u8* __restrict__ tmp8,
    const u64* __restrict__ maskb, float* __restrict__ outp) {
  __shared__ __align__(16) char lds[73728];
  const int tid = threadIdx.x;
  const int lane = tid & 63;
  const int wid = tid >> 6;
  const int fr = lane & 15;
  const int fq = lane >> 4;

  const int p = blockIdx.x;           // 512 blocks
  const int x = p & 7;
  const int i = p >> 3;               // 0..63
  const int thalf = i & 1;
  const int b = x * 32 + (i >> 1);

  const u8* Ab = e8 + (long long)b * 262144;
  const u8* Bb = tmp8 + (long long)b * 65536 + (long long)thalf * 64 * 512;

  const int srow = tid >> 2;  // 0..127
  const int sc = tid & 3;

#define STAGEA(dd, k0)                                                        \
  {                                                                           \
    _Pragma("unroll") for (int g_ = 0; g_ < 4; g_++) {                        \
      const int r_ = g_ * 128 + srow;                                         \
      GLOAD16(Ab + r_ * 512ll + (k0) + ((sc ^ ((r_ >> 1) & 3)) << 4),         \
              lds + (dd) * 32768 + g_ * 8192 + wid * 1024);                   \
    }                                                                         \
  }
#define STAGEB(dd, k0)                                                        \
  {                                                                           \
    _Pragma("unroll") for (int g_ = 0; g_ < 2; g_++) {                        \
      const int r_ = g_ * 32 + (tid >> 4);                                    \
      const int lb_ = (tid & 15) * 4;                                         \
      const int gb_ = ((((lb_ >> 4) ^ ((r_ >> 1) & 3))) << 4) | (lb_ & 15);   \
      GLOAD4(Bb + r_ * 512ll + (k0) + gb_,                                    \
             lds + 65536 + (dd) * 4096 + g_ * 2048 + wid * 256);              \
    }                                                                         \
  }
#define READ_A(dst, mb)                                                       \
  _Pragma("unroll") for (int ks = 0; ks < 2; ks++) {                          \
    const int r_ = wid * 64 + (mb) * 16 + fr;                                 \
    dst[ks] = *(const long*)(ab + r_ * 64 + (((ks * 4 + fq) ^ (r_ & 6)) << 3)); \
  }
#define MFMA_PH(src, mb)                                                      \
  _Pragma("unroll") for (int nb = 0; nb < 4; nb++)                            \
  _Pragma("unroll") for (int ks = 0; ks < 2; ks++)                            \
    acc[mb][nb] = mfma8(src[ks], bfrag[nb][ks], acc[mb][nb]);

  f32x4 acc[4][4];
#pragma unroll
  for (int ii = 0; ii < 4; ii++)
#pragma unroll
    for (int jj = 0; jj < 4; jj++) acc[ii][jj] = (f32x4){0.f, 0.f, 0.f, 0.f};

  STAGEB(0, 0); STAGEA(0, 0);
  STAGEB(1, 64); STAGEA(1, 64);

#pragma unroll 1
  for (int t = 0; t < 8; t++) {
    const int d = t & 1;
    if (t == 7) { WAITV(0); } else { WAITV(6); }
    HBAR; SBAR;

    const char* ab = lds + d * 32768;
    const char* bb = lds + 65536 + d * 4096;

    long bfrag[4][2];
#pragma unroll
    for (int nb = 0; nb < 4; nb++)
#pragma unroll
      for (int ks = 0; ks < 2; ks++) {
        const int brow = nb * 16 + fr;
        bfrag[nb][ks] =
            *(const long*)(bb + brow * 64 + (((ks * 4 + fq) ^ (brow & 6)) << 3));
      }
    long afA[2], afB[2];
    READ_A(afA, 0);
    WAITLGKM; SBAR;
    READ_A(afB, 1);
    __builtin_amdgcn_s_setprio(1);
    MFMA_PH(afA, 0);
    __builtin_amdgcn_s_setprio(0);
    WAITLGKM; SBAR;
    READ_A(afA, 2);
    __builtin_amdgcn_s_setprio(1);
    MFMA_PH(afB, 1);
    __builtin_amdgcn_s_setprio(0);
    WAITLGKM; SBAR;
    READ_A(afB, 3);
    __builtin_amdgcn_s_setprio(1);
    MFMA_PH(afA, 2);
    __builtin_amdgcn_s_setprio(0);
    WAITLGKM; SBAR;
    HBAR;
    if (t + 2 < 8) { STAGEB(d, (t + 2) * 64); STAGEA(d, (t + 2) * 64); }
    __builtin_amdgcn_s_setprio(1);
    MFMA_PH(afB, 3);
    __builtin_amdgcn_s_setprio(0);
  }
#undef STAGEA
#undef STAGEB
#undef READ_A
#undef MFMA_PH

  // ---- fused tanh/mask + log-softmax epilogue (acc = 8 * true logits-dot)
  float* red = (float*)lds;
  const float rs8 = 0.044194173824159216f * 0.125f;  // 1/sqrt(512)/8
  const float L2E = 1.4426950408889634f;

  float lmax[4];
#pragma unroll
  for (int nb = 0; nb < 4; nb++) {
    const int tl = nb * 16 + fr;
    const long long orow = (long long)b * 128 + thalf * 64 + tl;
    const u64 w = maskb[orow * 8 + wid];
    float mx = -3.0e38f;
#pragma unroll
    for (int mb = 0; mb < 4; mb++) {
      f32x4 r;
#pragma unroll
      for (int q = 0; q < 4; q++) {
        float xv = acc[mb][nb][q] * rs8;
        float e = exp2f(xv * 2.8853900817779268f);  // e^{2x}
        float th = 1.0f - 2.0f * __builtin_amdgcn_rcpf(e + 1.0f);
        float lg = 10.0f * th;
        const int bitn = mb * 16 + fq * 4 + q;
        if ((w >> bitn) & 1ull) lg = NEG_INF;
        r[q] = lg;
        mx = fmaxf(mx, lg);
      }
      acc[mb][nb] = r;
    }
    mx = fmaxf(mx, __shfl_xor(mx, 16));
    mx = fmaxf(mx, __shfl_xor(mx, 32));
    lmax[nb] = mx;
  }
  __syncthreads();
  if (lane < 16) {
#pragma unroll
    for (int nb = 0; nb < 4; nb++) red[wid * 64 + nb * 16 + lane] = lmax[nb];
  }
  __syncthreads();
  if (tid < 64) {
    float m = red[tid];
#pragma unroll
    for (int ww = 1; ww < 8; ww++) m = fmaxf(m, red[ww * 64 + tid]);
    red[512 + tid] = m;
  }
  __syncthreads();
  float lsum[4];
#pragma unroll
  for (int nb = 0; nb < 4; nb++) {
    const float m = red[512 + nb * 16 + fr];
    float s = 0.f;
#pragma unroll
    for (int mb = 0; mb < 4; mb++)
#pragma unroll
      for (int q = 0; q < 4; q++) s += exp2f((acc[mb][nb][q] - m) * L2E);
    s += __shfl_xor(s, 16);
    s += __shfl_xor(s, 32);
    lsum[nb] = s;
  }
  if (lane < 16) {
#pragma unroll
    for (int nb = 0; nb < 4; nb++) red[576 + wid * 64 + nb * 16 + lane] = lsum[nb];
  }
  __syncthreads();
  if (tid < 64) {
    float s = red[576 + tid];
#pragma unroll
    for (int ww = 1; ww < 8; ww++) s += red[576 + ww * 64 + tid];
    red[1088 + tid] = red[512 + tid] + logf(s);
  }
  __syncthreads();
#pragma unroll
  for (int nb = 0; nb < 4; nb++) {
    const int tl = nb * 16 + fr;
    const long long orow = (long long)b * 128 + thalf * 64 + tl;
    const float lse = red[1088 + tl];
#pragma unroll
    for (int mb = 0; mb < 4; mb++) {
      const int node0 = wid * 64 + mb * 16 + fq * 4;
      f32x4 r = acc[mb][nb];
#pragma unroll
      for (int q = 0; q < 4; q++) r[q] -= lse;
      *(f32x4*)&outp[orow * 512 + node0] = r;
    }
  }
}

// ---------------- small 128^2 GEMM (used once for WfT8 = fp8(WfT x 64))
__global__ __launch_bounds__(256) void gemm128_plain_kernel(
    const u16* __restrict__ A, const u16* __restrict__ Bv, u8* __restrict__ outp) {
  __shared__ u16 lA[128 * 32];
  __shared__ u16 lB[128 * 32];
  const int tid = threadIdx.x;
  const int lane = tid & 63;
  const int wave = tid >> 6;
  const int wr = wave >> 1, wc = wave & 1;

  const int p = blockIdx.x;  // grid 16
  const int wk = (p & 7) * 2 + (p >> 3);
  const int ntile = wk & 3;
  const int mtile = wk >> 2;
  const long long arow0 = (long long)mtile * 128;
  const long long brow0 = (long long)ntile * 128;

  f32x4 acc[4][4];
#pragma unroll
  for (int i = 0; i < 4; i++)
#pragma unroll
    for (int j = 0; j < 4; j++) acc[i][j] = (f32x4){0.f, 0.f, 0.f, 0.f};

  const int sc8 = (lane & 3) << 3;

  for (int k0 = 0; k0 < 512; k0 += 32) {
    __syncthreads();
#pragma unroll
    for (int i = 0; i < 2; i++) {
      GLOAD16(A + (arow0 + i * 64 + wave * 16 + (lane >> 2)) * 512ll + k0 + sc8,
              &lA[(i * 64 + wave * 16) * 32]);
      GLOAD16(Bv + (brow0 + i * 64 + wave * 16 + (lane >> 2)) * 512ll + k0 + sc8,
              &lB[(i * 64 + wave * 16) * 32]);
    }
    __syncthreads();
    s16x8 af[4], bfr[4];
#pragma unroll
    for (int i = 0; i < 4; i++)
      af[i] = *(const s16x8*)&lA[(wr * 64 + i * 16 + (lane & 15)) * 32 + ((lane >> 4) << 3)];
#pragma unroll
    for (int j = 0; j < 4; j++)
      bfr[j] = *(const s16x8*)&lB[(wc * 64 + j * 16 + (lane & 15)) * 32 + ((lane >> 4) << 3)];
#pragma unroll
    for (int i = 0; i < 4; i++)
#pragma unroll
      for (int j = 0; j < 4; j++) acc[i][j] = mfma16(af[i], bfr[j], acc[i][j]);
  }

#pragma unroll
  for (int i = 0; i < 4; i++) {
    const int rl = wr * 64 + i * 16 + ((lane >> 4) << 2);
#pragma unroll
    for (int j = 0; j < 4; j++) {
      const int cl = wc * 64 + j * 16 + (lane & 15);
#pragma unroll
      for (int q = 0; q < 4; q++)
        outp[(arow0 + rl + q) * 512 + brow0 + cl] = f2fp8(acc[i][j][q] * 64.0f);
    }
  }
}

// =============================================================================
// Fused attention v5 (fp8 end-to-end) — unchanged (round-16 form).
// Block = (b, h, t-half). 4096 blocks x 512 threads.
// =============================================================================
__global__ __launch_bounds__(512, 4) void attn_kernel(
    const u8* __restrict__ q8, const u8* __restrict__ K8,
    const u8* __restrict__ V8, const u64* __restrict__ maskbits,
    u8* __restrict__ o8buf) {
  __shared__ __align__(16) char lds[68864];
  char* Plds = lds + 32768;
  float* rsw = (float*)(lds + 66560);
  float* rst = (float*)(lds + 68608);

  const int p = blockIdx.x;           // 4096 blocks, 512/XCD
  const int fb = (p & 7) * 512 + (p >> 3);
  const int thalf = fb & 1;
  const int h = (fb >> 1) & 7;
  const int b = fb >> 4;
  const int bh = b * 8 + h;
  const int tid = threadIdx.x;
  const int lane = tid & 63;
  const int wid = tid >> 6;
  const int fr = lane & 15;
  const int fq = lane >> 4;
  const int tt0 = thalf * 64;

  // ---- stage V^T fp8 once; source = chunk layout, dest linear (wave-uniform)
  {
    const u8* Vb = V8 + (long long)bh * 32768;
#pragma unroll
    for (int it = 0; it < 4; it++) {
      const int Lc = it * 512 + wid * 64 + lane;  // LDS 16B-chunk index
      const int kk = Lc >> 5;
      const int s16p = Lc & 31;
      const int s16 = s16p ^ (kk & 7);            // logical node-group
      GLOAD16(Vb + (s16 * 64 + kk) * 16, lds + (it * 512 + wid * 64) * 16);
    }
  }

  const u8* Qb = q8 + ((long long)(b * 128 + tt0)) * 512 + h * 64;
  long qf[4][2];
#pragma unroll
  for (int tf = 0; tf < 4; tf++)
#pragma unroll
    for (int ks = 0; ks < 2; ks++)
      qf[tf][ks] = *(const long*)(Qb + (long long)(tf * 16 + fr) * 512 + ks * 32 + fq * 8);

  const int wstrip = wid * 64;
  const u8* Kb = K8 + ((long long)bh * 512 + wstrip) * 64;
  f32x4 s[4][4];
#pragma unroll
  for (int nf = 0; nf < 4; nf++)
#pragma unroll
    for (int tf = 0; tf < 4; tf++) s[nf][tf] = (f32x4){0.f, 0.f, 0.f, 0.f};
#pragma unroll
  for (int nf = 0; nf < 4; nf++) {
#pragma unroll
    for (int ks = 0; ks < 2; ks++) {
      long kf = *(const long*)(Kb + (long long)(nf * 16 + fr) * 64 + ks * 32 + fq * 8);
#pragma unroll
      for (int tf = 0; tf < 4; tf++) s[nf][tf] = mfma8(kf, qf[tf][ks], s[nf][tf]);
    }
  }

  // s_acc = 2*(q.k); true compat = (q.k)/8 -> exp2(s_acc * log2e/16)
  const float CE2 = 0.09016844005556021f;
  u64 mq[4];
#pragma unroll
  for (int tf = 0; tf < 4; tf++)
    mq[tf] = maskbits[((long long)(b * 128) + tt0 + tf * 16 + fr) * 8 + wid];
  float psum[4] = {0.f, 0.f, 0.f, 0.f};
#pragma unroll
  for (int nf = 0; nf < 4; nf++) {
#pragma unroll
    for (int tf = 0; tf < 4; tf++) {
      float pv[4];
#pragma unroll
      for (int q = 0; q < 4; q++) {
        const int bit = nf * 16 + fq * 4 + q;
        float v = exp2f(s[nf][tf][q] * CE2);
        if ((mq[tf] >> bit) & 1ull) v = 0.0f;
        psum[tf] += v;
        pv[q] = v;
      }
      const u32 pw = pk4_fp8(pv[0], pv[1], pv[2], pv[3]);
      const int t = tf * 16 + fr;
      const int o = wstrip + nf * 16 + fq * 4;
      const int s8 = o >> 3, lo = o & 7;
      *(u32*)(Plds + t * 528 + (((s8 ^ (t & 7)) << 3) | lo)) = pw;
    }
  }
#pragma unroll
  for (int tf = 0; tf < 4; tf++) {
    float v = psum[tf];
    v += __shfl_xor(v, 16);
    v += __shfl_xor(v, 32);
    if (lane < 16) rsw[(tf * 16 + lane) * 8 + wid] = v;
  }
  __syncthreads();  // P + rsw visible; V staging drained

  if (tid < 64) {
    float sum = rsw[tid * 8];
#pragma unroll
    for (int ww = 1; ww < 8; ww++) sum += rsw[tid * 8 + ww];
    rst[tid] = __builtin_amdgcn_rcpf(sum);
  }

  const int kkh = wid & 1;
  const int tts = wid >> 1;
  f32x4 o[2];
  o[0] = (f32x4){0.f, 0.f, 0.f, 0.f};
  o[1] = (f32x4){0.f, 0.f, 0.f, 0.f};
  const int tpv = tts * 16 + fr;
#pragma unroll
  for (int nstep = 0; nstep < 16; nstep++) {
    const int s8 = nstep * 4 + fq;
    long pf = *(const long*)(Plds + tpv * 528 + ((s8 ^ (tpv & 7)) << 3));
#pragma unroll
    for (int kf = 0; kf < 2; kf++) {
      const int kk = kkh * 32 + kf * 16 + fr;
      const int vs16 = s8 >> 1, vlo = s8 & 1;
      long vf = *(const long*)(lds + kk * 512 + (((vs16 ^ (kk & 7)) << 4) | (vlo << 3)));
      o[kf] = mfma8(vf, pf, o[kf]);
    }
  }
  __syncthreads();  // rst visible

  const float r4 = rst[tpv] * 4.0f;
  const long long orow = (long long)b * 128 + tt0 + tpv;
#pragma unroll
  for (int kf = 0; kf < 2; kf++) {
    const u32 pw = pk4_fp8(o[kf][0] * r4, o[kf][1] * r4, o[kf][2] * r4, o[kf][3] * r4);
    const int col = h * 64 + kkh * 32 + kf * 16 + fq * 4;
    *(u32*)&o8buf[orow * 512 + col] = pw;
  }
}

// ---------------------------------------------------------------- launch
extern "C" void kernel_launch(void* const* d_in, const int* in_sizes, int n_in,
                              void* d_out, int out_size, void* d_ws, size_t ws_size,
                              hipStream_t stream) {
  (void)in_sizes; (void)n_in; (void)out_size; (void)ws_size;
  const float* emb  = (const float*)d_in[0];
  const int*   cur  = (const int*)d_in[1];
  const float* ucap = (const float*)d_in[2];
  const float* ubat = (const float*)d_in[3];
  const float* ctim = (const float*)d_in[4];
  const void*  mask = d_in[5];
  const float* Wc   = (const float*)d_in[6];
  const float* Wkvl = (const float*)d_in[7];
  const float* Wstep= (const float*)d_in[8];
  const float* Wout = (const float*)d_in[9];

  char* w = (char*)d_ws;
  size_t off = 0;
  auto take = [&](size_t nbytes) -> char* {
    char* p = w + off;
    off += (nbytes + 255) & ~(size_t)255;
    return p;
  };
  unsigned char* maskb = (unsigned char*)take((size_t)256 * 128 * 64);   // 2 MB
  u8* e8               = (u8*)take((size_t)256 * 512 * 512);             // 67 MB fp8 emb
  u8* WkT8             = (u8*)take((size_t)1024 * 512);                  // fp8 x16
  u8* WstepT8          = (u8*)take((size_t)512 * 576);                   // fp8 x16
  u16* W2bf            = (u16*)take((size_t)512 * 512 * 2);
  u16* Woutbf          = (u16*)take((size_t)512 * 512 * 2);
  u8* WfT8             = (u8*)take((size_t)512 * 512);                   // fp8 x64
  float* pmean         = (float*)take((size_t)1024 * 512 * 4);
  float* fixedc        = (float*)take((size_t)256 * 512 * 4);
  u8* K8               = (u8*)take((size_t)256 * 8 * 512 * 64);          // 67 MB
  u8* V8               = (u8*)take((size_t)256 * 8 * 64 * 512);          // 67 MB
  u8* nextn8           = (u8*)take((size_t)32768 * 576);                 // 18.9 MB
  u8* q8               = (u8*)take((size_t)32768 * 512);                 // 16.8 MB
  u8* o8               = (u8*)take((size_t)32768 * 512);                 // 16.8 MB
  u8* tmp8             = (u8*)take((size_t)32768 * 512);                 // 16.8 MB

  maskprep_kernel<<<8192, 256, 0, stream>>>(mask, maskb);
  tcvt8_kernel<<<1024, 256, 0, stream>>>(Wkvl, 1536, 512, 512, WkT8);
  tcvt8_kernel<<<512, 256, 0, stream>>>(Wstep, 512, 515, 576, WstepT8);
  slice_cvt_kernel<<<1024, 256, 0, stream>>>(Wkvl, W2bf);
  cvt_bf_kernel<<<1024, 256, 0, stream>>>(Wout, Woutbf);
  gemm128_plain_kernel<<<16, 256, 0, stream>>>(W2bf, Woutbf, WfT8);
  cvt_pmean_kernel<<<1024, 256, 0, stream>>>(emb, e8, pmean);
  fixedctx_kernel<<<256, 256, 0, stream>>>(pmean, Wc, fixedc);
  build_nextn8_kernel<<<8192, 256, 0, stream>>>(e8, cur, ucap, ubat, ctim, nextn8);

  // KV projection (fp8 datapath, 3-deep pipeline, coalesced epilogue)
  gemm_kv8_kernel<<<512, 512, 0, stream>>>(e8, WkT8, K8, V8);
  // q8 = fp8( 2 * (fixedc + nextn8 @ WstepT8 / 16) ), K=576, NT=9
  gemm8_kernel<0><<<512, 512, 0, stream>>>(nextn8, WstepT8, 576, 576, 9, q8, fixedc);
  // attention v5 (fp8): block = (b, h, t-half)
  attn_kernel<<<4096, 512, 0, stream>>>(q8, K8, V8, (const u64*)maskb, o8);
  // tmp8 = fp8( (o8 @ WfT8) / 32 ) = 8 * true, K=512, NT=8
  gemm8_kernel<1><<<512, 512, 0, stream>>>(o8, WfT8, 512, 512, 8, tmp8, nullptr);
  // logits (fp8 GEMM) + tanh/mask + log-softmax fused -> f32 d_out
  gemm_lsm8_kernel<<<512, 512, 0, stream>>>(e8, tmp8, (const u64*)maskb, (float*)d_out);
}

// Round 18
// 455.518 us; speedup vs baseline: 1.0266x; 1.0266x over previous
//
#include <hip/hip_runtime.h>
#include <hip/hip_bf16.h>
#include <hip/hip_fp8.h>
#include <stdint.h>

typedef unsigned char  u8;
typedef unsigned short u16;
typedef unsigned int   u32;
typedef unsigned long long u64;
typedef __attribute__((ext_vector_type(4))) float f32x4;
typedef __attribute__((ext_vector_type(4))) unsigned int u32x4;
typedef __attribute__((ext_vector_type(8))) short s16x8;

#define NEG_INF (-1e9f)

__device__ __forceinline__ u16 f2bf(float f) {
  __hip_bfloat16 h = __float2bfloat16(f);
  return __builtin_bit_cast(u16, h);
}

__device__ __forceinline__ u8 f2fp8(float f) {
  __hip_fp8_e4m3 h(f);
  return (u8)h.__x;
}

// HW packed fp32->fp8 conversion (OCP on gfx950); safe fallback if absent.
#if defined(__has_builtin)
#if __has_builtin(__builtin_amdgcn_cvt_pk_fp8_f32)
#define HAVE_PK8 1
#endif
#endif

__device__ __forceinline__ u32 pk4_fp8(float a, float b, float c, float d) {
#ifdef HAVE_PK8
  int r = __builtin_amdgcn_cvt_pk_fp8_f32(a, b, 0, false);
  r = __builtin_amdgcn_cvt_pk_fp8_f32(c, d, r, true);
  return (u32)r;
#else
  return (u32)f2fp8(a) | ((u32)f2fp8(b) << 8) | ((u32)f2fp8(c) << 16) |
         ((u32)f2fp8(d) << 24);
#endif
}

__device__ __forceinline__ f32x4 mfma16(s16x8 a, s16x8 b, f32x4 c) {
  return __builtin_amdgcn_mfma_f32_16x16x32_bf16(a, b, c, 0, 0, 0);
}

__device__ __forceinline__ f32x4 mfma8(long a, long b, f32x4 c) {
  return __builtin_amdgcn_mfma_f32_16x16x32_fp8_fp8(a, b, c, 0, 0, 0);
}

// async global->LDS, 16 B per lane; LDS dest is wave-uniform base + lane*16
#define GLOAD16(g, l)                                                        \
  __builtin_amdgcn_global_load_lds(                                          \
      (const __attribute__((address_space(1))) unsigned int*)(g),            \
      (__attribute__((address_space(3))) unsigned int*)(l), 16, 0, 0)
// width-4 variant; LDS dest = base + lane*4
#define GLOAD4(g, l)                                                         \
  __builtin_amdgcn_global_load_lds(                                          \
      (const __attribute__((address_space(1))) unsigned int*)(g),            \
      (__attribute__((address_space(3))) unsigned int*)(l), 4, 0, 0)

#define WAITV(n) asm volatile("s_waitcnt vmcnt(" #n ")" ::: "memory")
#define WAITLGKM asm volatile("s_waitcnt lgkmcnt(0)" ::: "memory")
#define SBAR __builtin_amdgcn_sched_barrier(0)
#define HBAR __builtin_amdgcn_s_barrier()

// ------------------------------------------- mask prep (fused dtype detect)
__global__ __launch_bounds__(256) void maskprep_kernel(const void* __restrict__ mraw,
                                                       unsigned char* __restrict__ mb) {
  __shared__ int anyS;
  const int tid = threadIdx.x;
  int loc = 0;
  {
    u32 v = ((const u32*)mraw)[tid];
    if (v & 0xFFFFFF00u) loc = 1;  // int32 0/1 never sets high bytes
  }
  if (tid == 0) anyS = 0;
  __syncthreads();
  if (loc) atomicOr(&anyS, 1);
  __syncthreads();
  const int is1byte = anyS;

  long long idx = (long long)blockIdx.x * 256 + tid;  // B*T*64 = 2097152
  long long bt = idx >> 6;
  int ch = (int)(idx & 63);
  unsigned char byte = 0;
  if (is1byte) {
    u64 v = *(const u64*)((const unsigned char*)mraw + bt * 512 + ch * 8);
#pragma unroll
    for (int i = 0; i < 8; i++)
      if ((v >> (8 * i)) & 0xFFull) byte |= (unsigned char)(1 << i);
  } else {
    const int* p = (const int*)mraw + bt * 512 + ch * 8;
#pragma unroll
    for (int i = 0; i < 8; i++)
      if (p[i]) byte |= (unsigned char)(1 << i);
  }
  mb[idx] = byte;
}

// ---------------------------------------------------------------- weight prep
__global__ void tcvt8_kernel(const float* __restrict__ in, int ld_in, int kreal,
                             int CO, u8* __restrict__ outp) {
  int i = blockIdx.x;
  for (int j = threadIdx.x; j < CO; j += 256) {
    float v = (j < kreal) ? in[(long long)j * ld_in + i] * 16.0f : 0.0f;
    outp[(long long)i * CO + j] = f2fp8(v);
  }
}

__global__ void slice_cvt_kernel(const float* __restrict__ in, u16* __restrict__ outp) {
  long long idx = (long long)blockIdx.x * 256 + threadIdx.x;  // 262144
  long long dd = idx >> 9;
  int hh = (int)(idx & 511);
  outp[idx] = f2bf(in[dd * 1536 + 1024 + hh]);
}

__global__ void cvt_bf_kernel(const float* __restrict__ in, u16* __restrict__ outp) {
  long long idx = (long long)blockIdx.x * 256 + threadIdx.x;
  outp[idx] = f2bf(in[idx]);
}

// ---------------- emb fp32 -> fp8 + partial mean (fused)
__global__ __launch_bounds__(256) void cvt_pmean_kernel(const float* __restrict__ emb,
                                                        u8* __restrict__ e8,
                                                        float* __restrict__ pmean) {
  const int bq = blockIdx.x >> 2, nq = blockIdx.x & 3;
  const int tid = threadIdx.x;
  const int ro = tid >> 7;
  const int c4 = (tid & 127) << 2;
  const long long base = ((long long)bq * 512 + nq * 128) * 512;
  float s[4] = {0.f, 0.f, 0.f, 0.f};
  for (int n = ro; n < 128; n += 2) {
    f32x4 v = *(const f32x4*)&emb[base + (long long)n * 512 + c4];
#pragma unroll
    for (int i = 0; i < 4; i++) s[i] += v[i];
    *(u32*)&e8[base + (long long)n * 512 + c4] = pk4_fp8(v[0], v[1], v[2], v[3]);
  }
  __shared__ float ls[2][512];
#pragma unroll
  for (int i = 0; i < 4; i++) ls[ro][c4 + i] = s[i];
  __syncthreads();
  float* dst = pmean + (long long)blockIdx.x * 512;
  dst[tid] = ls[0][tid] + ls[1][tid];
  dst[tid + 256] = ls[0][tid + 256] + ls[1][tid + 256];
}

__global__ __launch_bounds__(256) void fixedctx_kernel(const float* __restrict__ pmean,
                                                       const float* __restrict__ Wc,
                                                       float* __restrict__ fixedc) {
  __shared__ float mf[512];
  int b = blockIdx.x;
  const float* p = pmean + (long long)b * 4 * 512;
  for (int d = threadIdx.x; d < 512; d += 256)
    mf[d] = (p[d] + p[512 + d] + p[1024 + d] + p[1536 + d]) * (1.0f / 512.0f);
  __syncthreads();
  for (int h = threadIdx.x; h < 512; h += 256) {
    float s = 0.f;
    for (int d = 0; d < 512; ++d) s += mf[d] * Wc[(long long)d * 512 + h];
    fixedc[(long long)b * 512 + h] = s;
  }
}

// -------------------------------- next-node features, fp8 (gather from e8, ld 576)
__global__ __launch_bounds__(256) void build_nextn8_kernel(
    const u8* __restrict__ e8, const int* __restrict__ cur,
    const float* __restrict__ ucap, const float* __restrict__ ubat,
    const float* __restrict__ ctim, u8* __restrict__ outp) {
  const long long rowm = (long long)blockIdx.x * 4 + (threadIdx.x >> 6);
  const int lane = threadIdx.x & 63;
  const int b = (int)(rowm >> 7);
  const int node = cur[rowm];
  const u8* src = e8 + ((long long)b * 512 + node) * 512;
  u8* dst = outp + rowm * 576;
  *(u64*)&dst[lane * 8] = *(const u64*)&src[lane * 8];
  if (lane < 8) {
    u64 v = 0;
    if (lane == 0) {
      v = (u64)f2fp8(1.0f - ucap[rowm]) | ((u64)f2fp8(1.0f - ubat[rowm]) << 8) |
          ((u64)f2fp8(ctim[rowm]) << 16);
    }
    *(u64*)&dst[512 + lane * 8] = v;
  }
}

// =============================================================================
// KV projection GEMM (fp8, coalesced epilogue) — round-16 form (2-deep, 57.3 KB)
// =============================================================================
__global__ __launch_bounds__(512, 4) void gemm_kv8_kernel(
    const u8* __restrict__ A8, const u8* __restrict__ Bw8,
    u8* __restrict__ K8, u8* __restrict__ V8) {
  __shared__ __align__(16) char lds[57344];  // 48 KB stage + 8 KB epilogue tiles
  const int tid = threadIdx.x;
  const int lane = tid & 63;
  const int wid = tid >> 6;
  const int wr = wid >> 1, wc = wid & 1;  // 4M x 2N
  const int fr = lane & 15;
  const int fq = lane >> 4;

  const int p = blockIdx.x;   // 512 blocks, 64/XCD
  const int x = p & 7;
  const int i = p >> 3;       // 0..63
  const int ntile = i & 7;    // N = 1024 / 128
  const int mgrp = i >> 3;    // 0..7
  const long long nrow0 = (long long)ntile * 128;

  const int srow = tid >> 2;  // 0..127 staging row
  const int sc = tid & 3;     // 16B chunk

#define MROW(tt2) (((long long)x * 64 + mgrp * 8 + ((tt2) >> 3)) * 256)
#define KOF(tt2) (((tt2) & 7) * 64)

#define STAGEA(dd, tt2)                                                       \
  {                                                                           \
    _Pragma("unroll") for (int g_ = 0; g_ < 2; g_++) {                        \
      const int r_ = g_ * 128 + srow;                                         \
      GLOAD16(A8 + (MROW(tt2) + r_) * 512ll + KOF(tt2) +                      \
                  ((sc ^ ((r_ >> 1) & 3)) << 4),                              \
              lds + (dd) * 24576 + g_ * 8192 + wid * 1024);                   \
    }                                                                         \
  }
#define STAGEB(dd, tt2)                                                       \
  {                                                                           \
    GLOAD16(Bw8 + (nrow0 + srow) * 512ll + KOF(tt2) +                         \
                ((sc ^ ((srow >> 1) & 3)) << 4),                              \
            lds + (dd) * 24576 + 16384 + wid * 1024);                         \
  }

#define READ_A(dst, mb)                                                       \
  _Pragma("unroll") for (int ks = 0; ks < 2; ks++) {                          \
    const int r_ = wr * 64 + (mb) * 16 + fr;                                  \
    dst[ks] = *(const long*)(ab + r_ * 64 + (((ks * 4 + fq) ^ (r_ & 6)) << 3)); \
  }
#define MFMA_PH(src, mb)                                                      \
  _Pragma("unroll") for (int nb = 0; nb < 4; nb++)                            \
  _Pragma("unroll") for (int ks = 0; ks < 2; ks++)                            \
    acc[mb][nb] = mfma8(src[ks], bfrag[nb][ks], acc[mb][nb]);

  STAGEB(0, 0); STAGEA(0, 0);
  STAGEB(1, 1); STAGEA(1, 1);

  f32x4 acc[4][4];
  char* tile = lds + 49152 + wid * 1024;
  const int hh = (ntile * 2 + wc) & 7;

#pragma unroll 1
  for (int u = 0; u < 8; u++) {
#pragma unroll
    for (int ii = 0; ii < 4; ii++)
#pragma unroll
      for (int jj = 0; jj < 4; jj++) acc[ii][jj] = (f32x4){0.f, 0.f, 0.f, 0.f};

#pragma unroll 1
    for (int t8 = 0; t8 < 8; t8++) {
      const int tt = u * 8 + t8;
      const int d = tt & 1;
      if (tt == 63) { WAITV(0); } else { WAITV(3); }
      HBAR; SBAR;

      const char* ab = lds + d * 24576;
      const char* bb = lds + d * 24576 + 16384;

      long bfrag[4][2];
#pragma unroll
      for (int nb = 0; nb < 4; nb++)
#pragma unroll
        for (int ks = 0; ks < 2; ks++) {
          const int brow = wc * 64 + nb * 16 + fr;
          bfrag[nb][ks] =
              *(const long*)(bb + brow * 64 + (((ks * 4 + fq) ^ (brow & 6)) << 3));
        }
      long afA[2], afB[2];
      READ_A(afA, 0);
      WAITLGKM; SBAR;
      READ_A(afB, 1);
      __builtin_amdgcn_s_setprio(1);
      MFMA_PH(afA, 0);
      __builtin_amdgcn_s_setprio(0);
      WAITLGKM; SBAR;
      READ_A(afA, 2);
      __builtin_amdgcn_s_setprio(1);
      MFMA_PH(afB, 1);
      __builtin_amdgcn_s_setprio(0);
      WAITLGKM; SBAR;
      READ_A(afB, 3);
      __builtin_amdgcn_s_setprio(1);
      MFMA_PH(afA, 2);
      __builtin_amdgcn_s_setprio(0);
      WAITLGKM; SBAR;
      HBAR;
      if (tt + 2 < 64) { STAGEB(d, tt + 2); STAGEA(d, tt + 2); }
      __builtin_amdgcn_s_setprio(1);
      MFMA_PH(afB, 3);
      __builtin_amdgcn_s_setprio(0);
    }

    // ---- coalesced epilogue via per-wave LDS transpose tile ----
    const long long mrow0 = MROW(u * 8);
    const int bbx = (int)(mrow0 >> 9);
    const int nodeb = (int)(mrow0 & 511);
    const long long bhoff = ((long long)(bbx * 8 + hh)) << 15;

    if (ntile < 4) {
      // K path: tile logical [16 node][64 kk] bytes, dword-XOR swizzled
#pragma unroll
      for (int mb = 0; mb < 4; mb++) {
#pragma unroll
        for (int nb = 0; nb < 4; nb++) {
          const u32 pw = pk4_fp8(acc[mb][nb][0] * 0.0625f, acc[mb][nb][1] * 0.0625f,
                                 acc[mb][nb][2] * 0.0625f, acc[mb][nb][3] * 0.0625f);
          const int colhi = (nb * 16 + (fr & ~3));
          const int collo = fr & 3;
#pragma unroll
          for (int q = 0; q < 4; q++) {
            const int row = fq * 4 + q;
            tile[row * 64 + (colhi ^ ((row & 15) << 2)) + collo] = (u8)(pw >> (8 * q));
          }
        }
        WAITLGKM; SBAR;
        const int row = lane >> 2;
        u32x4 val;
#pragma unroll
        for (int j = 0; j < 4; j++) {
          const int dw = ((lane & 3) * 4 + j) << 2;
          val[j] = *(const u32*)(tile + row * 64 + (dw ^ ((row & 15) << 2)));
        }
        WAITLGKM; SBAR;
        u8* dst = K8 + bhoff + (long long)(nodeb + wr * 64 + mb * 16) * 64;
        *(u32x4*)(dst + lane * 16) = val;
      }
    } else {
      // V path: tile [64 kk][16 node] bytes; u32 writes along node.
#pragma unroll
      for (int mb = 0; mb < 4; mb++) {
#pragma unroll
        for (int nb = 0; nb < 4; nb++) {
          const u32 pw = pk4_fp8(acc[mb][nb][0] * 0.0625f, acc[mb][nb][1] * 0.0625f,
                                 acc[mb][nb][2] * 0.0625f, acc[mb][nb][3] * 0.0625f);
          *(u32*)(tile + (nb * 16 + fr) * 16 + fq * 4) = pw;
        }
        WAITLGKM; SBAR;
        u32x4 val = *(const u32x4*)(tile + lane * 16);  // kk = lane
        WAITLGKM; SBAR;
        const int ngrp = (nodeb + wr * 64 + mb * 16) >> 4;
        u8* dst = V8 + bhoff + (long long)ngrp * 1024;
        *(u32x4*)(dst + lane * 16) = val;
      }
    }
  }
#undef STAGEA
#undef STAGEB
#undef READ_A
#undef MFMA_PH
#undef MROW
#undef KOF
}

// =============================================================================
// gemm8: generic fp8 GEMM
// MODE 0 (query): out = fp8( (acc/16 + fixedc[b][col]) * 2 )   [q8 = 2q]
// MODE 1 (tmp):   out = fp8( acc / 32 )                        [tmp8 = 8*true]
// =============================================================================
template <int MODE>
__global__ __launch_bounds__(512, 4) void gemm8_kernel(
    const u8* __restrict__ A8, const u8* __restrict__ B8,
    int ldA, int ldB, int NT,
    u8* __restrict__ out0, const float* __restrict__ aux) {
  __shared__ __align__(16) char lds[49152];
  const int tid = threadIdx.x;
  const int lane = tid & 63;
  const int wid = tid >> 6;
  const int wr = wid >> 1, wc = wid & 1;
  const int fr = lane & 15;
  const int fq = lane >> 4;

  const int p = blockIdx.x;          // 512
  const int wk = (p & 7) * 64 + (p >> 3);
  const int mtile = wk >> 2;
  const int ntile = wk & 3;
  const long long mrow0 = (long long)mtile * 256;
  const long long nrow0 = (long long)ntile * 128;

  const int srow = tid >> 2;
  const int sc = tid & 3;

#define STAGEA8(dd, k0)                                                       \
  {                                                                           \
    _Pragma("unroll") for (int g_ = 0; g_ < 2; g_++) {                        \
      const int r_ = g_ * 128 + srow;                                         \
      GLOAD16(A8 + (mrow0 + r_) * (long long)ldA + (k0) +                     \
                  ((sc ^ ((r_ >> 1) & 3)) << 4),                              \
              lds + (dd) * 24576 + g_ * 8192 + wid * 1024);                   \
    }                                                                         \
  }
#define STAGEB8(dd, k0)                                                       \
  {                                                                           \
    GLOAD16(B8 + (nrow0 + srow) * (long long)ldB + (k0) +                     \
                ((sc ^ ((srow >> 1) & 3)) << 4),                              \
            lds + (dd) * 24576 + 16384 + wid * 1024);                         \
  }
#define READ_A8(dst, mb)                                                      \
  _Pragma("unroll") for (int ks = 0; ks < 2; ks++) {                          \
    const int r_ = wr * 64 + (mb) * 16 + fr;                                  \
    dst[ks] = *(const long*)(ab + r_ * 64 + (((ks * 4 + fq) ^ (r_ & 6)) << 3)); \
  }
#define MFMA_PH8(src, mb)                                                     \
  _Pragma("unroll") for (int nb = 0; nb < 4; nb++)                            \
  _Pragma("unroll") for (int ks = 0; ks < 2; ks++)                            \
    acc[mb][nb] = mfma8(src[ks], bfrag[nb][ks], acc[mb][nb]);

  f32x4 acc[4][4];
#pragma unroll
  for (int ii = 0; ii < 4; ii++)
#pragma unroll
    for (int jj = 0; jj < 4; jj++) acc[ii][jj] = (f32x4){0.f, 0.f, 0.f, 0.f};

  STAGEB8(0, 0); STAGEA8(0, 0);
  STAGEB8(1, 64); STAGEA8(1, 64);

#pragma unroll 1
  for (int t = 0; t < NT; t++) {
    const int d = t & 1;
    if (t == NT - 1) { WAITV(0); } else { WAITV(3); }
    HBAR; SBAR;

    const char* ab = lds + d * 24576;
    const char* bb = lds + d * 24576 + 16384;

    long bfrag[4][2];
#pragma unroll
    for (int nb = 0; nb < 4; nb++)
#pragma unroll
      for (int ks = 0; ks < 2; ks++) {
        const int brow = wc * 64 + nb * 16 + fr;
        bfrag[nb][ks] =
            *(const long*)(bb + brow * 64 + (((ks * 4 + fq) ^ (brow & 6)) << 3));
      }
    long afA[2], afB[2];
    READ_A8(afA, 0);
    WAITLGKM; SBAR;
    READ_A8(afB, 1);
    __builtin_amdgcn_s_setprio(1);
    MFMA_PH8(afA, 0);
    __builtin_amdgcn_s_setprio(0);
    WAITLGKM; SBAR;
    READ_A8(afA, 2);
    __builtin_amdgcn_s_setprio(1);
    MFMA_PH8(afB, 1);
    __builtin_amdgcn_s_setprio(0);
    WAITLGKM; SBAR;
    READ_A8(afB, 3);
    __builtin_amdgcn_s_setprio(1);
    MFMA_PH8(afA, 2);
    __builtin_amdgcn_s_setprio(0);
    WAITLGKM; SBAR;
    HBAR;
    if (t + 2 < NT) { STAGEB8(d, (t + 2) * 64); STAGEA8(d, (t + 2) * 64); }
    __builtin_amdgcn_s_setprio(1);
    MFMA_PH8(afB, 3);
    __builtin_amdgcn_s_setprio(0);
  }
#undef STAGEA8
#undef STAGEB8
#undef READ_A8
#undef MFMA_PH8

  const int colbase = (int)(ntile * 128) + wc * 64;
#pragma unroll
  for (int mb = 0; mb < 4; mb++) {
    const long long row0 = mrow0 + wr * 64 + mb * 16 + fq * 4;
#pragma unroll
    for (int nb = 0; nb < 4; nb++) {
      const int col = colbase + nb * 16 + fr;
      u32 pw;
      if (MODE == 0) {
        float v0 = acc[mb][nb][0] * 0.0625f + aux[((row0 + 0) >> 7) * 512 + col];
        float v1 = acc[mb][nb][1] * 0.0625f + aux[((row0 + 1) >> 7) * 512 + col];
        float v2 = acc[mb][nb][2] * 0.0625f + aux[((row0 + 2) >> 7) * 512 + col];
        float v3 = acc[mb][nb][3] * 0.0625f + aux[((row0 + 3) >> 7) * 512 + col];
        pw = pk4_fp8(v0 * 2.0f, v1 * 2.0f, v2 * 2.0f, v3 * 2.0f);
      } else {
        pw = pk4_fp8(acc[mb][nb][0] * 0.03125f, acc[mb][nb][1] * 0.03125f,
                     acc[mb][nb][2] * 0.03125f, acc[mb][nb][3] * 0.03125f);
      }
#pragma unroll
      for (int q = 0; q < 4; q++)
        out0[(row0 + q) * 512 + col] = (u8)(pw >> (8 * q));
    }
  }
}

// =============================================================================
// gemm_lsm8
// =============================================================================
__global__ __launch_bounds__(512, 4) void gemm_lsm8_kernel(
    const u8* __restrict__ e8, const u8* __restrict__ tmp8,
    const u64* __restrict__ maskb, float* __restrict__ outp) {
  __shared__ __align__(16) char lds[73728];
  const int tid = threadIdx.x;
  const int lane = tid & 63;
  const int wid = tid >> 6;
  const int fr = lane & 15;
  const int fq = lane >> 4;

  const int p = blockIdx.x;           // 512 blocks
  const int x = p & 7;
  const int i = p >> 3;               // 0..63
  const int thalf = i & 1;
  const int b = x * 32 + (i >> 1);

  const u8* Ab = e8 + (long long)b * 262144;
  const u8* Bb = tmp8 + (long long)b * 65536 + (long long)thalf * 64 * 512;

  const int srow = tid >> 2;  // 0..127
  const int sc = tid & 3;

#define STAGEA(dd, k0)                                                        \
  {                                                                           \
    _Pragma("unroll") for (int g_ = 0; g_ < 4; g_++) {                        \
      const int r_ = g_ * 128 + srow;                                         \
      GLOAD16(Ab + r_ * 512ll + (k0) + ((sc ^ ((r_ >> 1) & 3)) << 4),         \
              lds + (dd) * 32768 + g_ * 8192 + wid * 1024);                   \
    }                                                                         \
  }
#define STAGEB(dd, k0)                                                        \
  {                                                                           \
    _Pragma("unroll") for (int g_ = 0; g_ < 2; g_++) {                        \
      const int r_ = g_ * 32 + (tid >> 4);                                    \
      const int lb_ = (tid & 15) * 4;                                         \
      const int gb_ = ((((lb_ >> 4) ^ ((r_ >> 1) & 3))) << 4) | (lb_ & 15);   \
      GLOAD4(Bb + r_ * 512ll + (k0) + gb_,                                    \
             lds + 65536 + (dd) * 4096 + g_ * 2048 + wid * 256);              \
    }                                                                         \
  }
#define READ_A(dst, mb)                                                       \
  _Pragma("unroll") for (int ks = 0; ks < 2; ks++) {                          \
    const int r_ = wid * 64 + (mb) * 16 + fr;                                 \
    dst[ks] = *(const long*)(ab + r_ * 64 + (((ks * 4 + fq) ^ (r_ & 6)) << 3)); \
  }
#define MFMA_PH(src, mb)                                                      \
  _Pragma("unroll") for (int nb = 0; nb < 4; nb++)                            \
  _Pragma("unroll") for (int ks = 0; ks < 2; ks++)                            \
    acc[mb][nb] = mfma8(src[ks], bfrag[nb][ks], acc[mb][nb]);

  f32x4 acc[4][4];
#pragma unroll
  for (int ii = 0; ii < 4; ii++)
#pragma unroll
    for (int jj = 0; jj < 4; jj++) acc[ii][jj] = (f32x4){0.f, 0.f, 0.f, 0.f};

  STAGEB(0, 0); STAGEA(0, 0);
  STAGEB(1, 64); STAGEA(1, 64);

#pragma unroll 1
  for (int t = 0; t < 8; t++) {
    const int d = t & 1;
    if (t == 7) { WAITV(0); } else { WAITV(6); }
    HBAR; SBAR;

    const char* ab = lds + d * 32768;
    const char* bb = lds + 65536 + d * 4096;

    long bfrag[4][2];
#pragma unroll
    for (int nb = 0; nb < 4; nb++)
#pragma unroll
      for (int ks = 0; ks < 2; ks++) {
        const int brow = nb * 16 + fr;
        bfrag[nb][ks] =
            *(const long*)(bb + brow * 64 + (((ks * 4 + fq) ^ (brow & 6)) << 3));
      }
    long afA[2], afB[2];
    READ_A(afA, 0);
    WAITLGKM; SBAR;
    READ_A(afB, 1);
    __builtin_amdgcn_s_setprio(1);
    MFMA_PH(afA, 0);
    __builtin_amdgcn_s_setprio(0);
    WAITLGKM; SBAR;
    READ_A(afA, 2);
    __builtin_amdgcn_s_setprio(1);
    MFMA_PH(afB, 1);
    __builtin_amdgcn_s_setprio(0);
    WAITLGKM; SBAR;
    READ_A(afB, 3);
    __builtin_amdgcn_s_setprio(1);
    MFMA_PH(afA, 2);
    __builtin_amdgcn_s_setprio(0);
    WAITLGKM; SBAR;
    HBAR;
    if (t + 2 < 8) { STAGEB(d, (t + 2) * 64); STAGEA(d, (t + 2) * 64); }
    __builtin_amdgcn_s_setprio(1);
    MFMA_PH(afB, 3);
    __builtin_amdgcn_s_setprio(0);
  }
#undef STAGEA
#undef STAGEB
#undef READ_A
#undef MFMA_PH

  // ---- fused tanh/mask + log-softmax epilogue (acc = 8 * true logits-dot)
  float* red = (float*)lds;
  const float rs8 = 0.044194173824159216f * 0.125f;  // 1/sqrt(512)/8
  const float L2E = 1.4426950408889634f;

  float lmax[4];
#pragma unroll
  for (int nb = 0; nb < 4; nb++) {
    const int tl = nb * 16 + fr;
    const long long orow = (long long)b * 128 + thalf * 64 + tl;
    const u64 w = maskb[orow * 8 + wid];
    float mx = -3.0e38f;
#pragma unroll
    for (int mb = 0; mb < 4; mb++) {
      f32x4 r;
#pragma unroll
      for (int q = 0; q < 4; q++) {
        float xv = acc[mb][nb][q] * rs8;
        float e = exp2f(xv * 2.8853900817779268f);  // e^{2x}
        float th = 1.0f - 2.0f * __builtin_amdgcn_rcpf(e + 1.0f);
        float lg = 10.0f * th;
        const int bitn = mb * 16 + fq * 4 + q;
        if ((w >> bitn) & 1ull) lg = NEG_INF;
        r[q] = lg;
        mx = fmaxf(mx, lg);
      }
      acc[mb][nb] = r;
    }
    mx = fmaxf(mx, __shfl_xor(mx, 16));
    mx = fmaxf(mx, __shfl_xor(mx, 32));
    lmax[nb] = mx;
  }
  __syncthreads();
  if (lane < 16) {
#pragma unroll
    for (int nb = 0; nb < 4; nb++) red[wid * 64 + nb * 16 + lane] = lmax[nb];
  }
  __syncthreads();
  if (tid < 64) {
    float m = red[tid];
#pragma unroll
    for (int ww = 1; ww < 8; ww++) m = fmaxf(m, red[ww * 64 + tid]);
    red[512 + tid] = m;
  }
  __syncthreads();
  float lsum[4];
#pragma unroll
  for (int nb = 0; nb < 4; nb++) {
    const float m = red[512 + nb * 16 + fr];
    float s = 0.f;
#pragma unroll
    for (int mb = 0; mb < 4; mb++)
#pragma unroll
      for (int q = 0; q < 4; q++) s += exp2f((acc[mb][nb][q] - m) * L2E);
    s += __shfl_xor(s, 16);
    s += __shfl_xor(s, 32);
    lsum[nb] = s;
  }
  if (lane < 16) {
#pragma unroll
    for (int nb = 0; nb < 4; nb++) red[576 + wid * 64 + nb * 16 + lane] = lsum[nb];
  }
  __syncthreads();
  if (tid < 64) {
    float s = red[576 + tid];
#pragma unroll
    for (int ww = 1; ww < 8; ww++) s += red[576 + ww * 64 + tid];
    red[1088 + tid] = red[512 + tid] + logf(s);
  }
  __syncthreads();
#pragma unroll
  for (int nb = 0; nb < 4; nb++) {
    const int tl = nb * 16 + fr;
    const long long orow = (long long)b * 128 + thalf * 64 + tl;
    const float lse = red[1088 + tl];
#pragma unroll
    for (int mb = 0; mb < 4; mb++) {
      const int node0 = wid * 64 + mb * 16 + fq * 4;
      f32x4 r = acc[mb][nb];
#pragma unroll
      for (int q = 0; q < 4; q++) r[q] -= lse;
      *(f32x4*)&outp[orow * 512 + node0] = r;
    }
  }
}

// ---------------- small 128^2 GEMM (used once for WfT8 = fp8(WfT x 64))
__global__ __launch_bounds__(256) void gemm128_plain_kernel(
    const u16* __restrict__ A, const u16* __restrict__ Bv, u8* __restrict__ outp) {
  __shared__ u16 lA[128 * 32];
  __shared__ u16 lB[128 * 32];
  const int tid = threadIdx.x;
  const int lane = tid & 63;
  const int wave = tid >> 6;
  const int wr = wave >> 1, wc = wave & 1;

  const int p = blockIdx.x;  // grid 16
  const int wk = (p & 7) * 2 + (p >> 3);
  const int ntile = wk & 3;
  const int mtile = wk >> 2;
  const long long arow0 = (long long)mtile * 128;
  const long long brow0 = (long long)ntile * 128;

  f32x4 acc[4][4];
#pragma unroll
  for (int i = 0; i < 4; i++)
#pragma unroll
    for (int j = 0; j < 4; j++) acc[i][j] = (f32x4){0.f, 0.f, 0.f, 0.f};

  const int sc8 = (lane & 3) << 3;

  for (int k0 = 0; k0 < 512; k0 += 32) {
    __syncthreads();
#pragma unroll
    for (int i = 0; i < 2; i++) {
      GLOAD16(A + (arow0 + i * 64 + wave * 16 + (lane >> 2)) * 512ll + k0 + sc8,
              &lA[(i * 64 + wave * 16) * 32]);
      GLOAD16(Bv + (brow0 + i * 64 + wave * 16 + (lane >> 2)) * 512ll + k0 + sc8,
              &lB[(i * 64 + wave * 16) * 32]);
    }
    __syncthreads();
    s16x8 af[4], bfr[4];
#pragma unroll
    for (int i = 0; i < 4; i++)
      af[i] = *(const s16x8*)&lA[(wr * 64 + i * 16 + (lane & 15)) * 32 + ((lane >> 4) << 3)];
#pragma unroll
    for (int j = 0; j < 4; j++)
      bfr[j] = *(const s16x8*)&lB[(wc * 64 + j * 16 + (lane & 15)) * 32 + ((lane >> 4) << 3)];
#pragma unroll
    for (int i = 0; i < 4; i++)
#pragma unroll
      for (int j = 0; j < 4; j++) acc[i][j] = mfma16(af[i], bfr[j], acc[i][j]);
  }

#pragma unroll
  for (int i = 0; i < 4; i++) {
    const int rl = wr * 64 + i * 16 + ((lane >> 4) << 2);
#pragma unroll
    for (int j = 0; j < 4; j++) {
      const int cl = wc * 64 + j * 16 + (lane & 15);
#pragma unroll
      for (int q = 0; q < 4; q++)
        outp[(arow0 + rl + q) * 512 + brow0 + cl] = f2fp8(acc[i][j][q] * 64.0f);
    }
  }
}

// =============================================================================
// Fused attention v5 (fp8 end-to-end) — round-16 form.
// Block = (b, h, t-half). 4096 blocks x 512 threads.
// =============================================================================
__global__ __launch_bounds__(512, 4) void attn_kernel(
    const u8* __restrict__ q8, const u8* __restrict__ K8,
    const u8* __restrict__ V8, const u64* __restrict__ maskbits,
    u8* __restrict__ o8buf) {
  __shared__ __align__(16) char lds[68864];
  char* Plds = lds + 32768;
  float* rsw = (float*)(lds + 66560);
  float* rst = (float*)(lds + 68608);

  const int p = blockIdx.x;           // 4096 blocks, 512/XCD
  const int fb = (p & 7) * 512 + (p >> 3);
  const int thalf = fb & 1;
  const int h = (fb >> 1) & 7;
  const int b = fb >> 4;
  const int bh = b * 8 + h;
  const int tid = threadIdx.x;
  const int lane = tid & 63;
  const int wid = tid >> 6;
  const int fr = lane & 15;
  const int fq = lane >> 4;
  const int tt0 = thalf * 64;

  // ---- stage V^T fp8 once; source = chunk layout, dest linear (wave-uniform)
  {
    const u8* Vb = V8 + (long long)bh * 32768;
#pragma unroll
    for (int it = 0; it < 4; it++) {
      const int Lc = it * 512 + wid * 64 + lane;  // LDS 16B-chunk index
      const int kk = Lc >> 5;
      const int s16p = Lc & 31;
      const int s16 = s16p ^ (kk & 7);            // logical node-group
      GLOAD16(Vb + (s16 * 64 + kk) * 16, lds + (it * 512 + wid * 64) * 16);
    }
  }

  const u8* Qb = q8 + ((long long)(b * 128 + tt0)) * 512 + h * 64;
  long qf[4][2];
#pragma unroll
  for (int tf = 0; tf < 4; tf++)
#pragma unroll
    for (int ks = 0; ks < 2; ks++)
      qf[tf][ks] = *(const long*)(Qb + (long long)(tf * 16 + fr) * 512 + ks * 32 + fq * 8);

  const int wstrip = wid * 64;
  const u8* Kb = K8 + ((long long)bh * 512 + wstrip) * 64;
  f32x4 s[4][4];
#pragma unroll
  for (int nf = 0; nf < 4; nf++)
#pragma unroll
    for (int tf = 0; tf < 4; tf++) s[nf][tf] = (f32x4){0.f, 0.f, 0.f, 0.f};
#pragma unroll
  for (int nf = 0; nf < 4; nf++) {
#pragma unroll
    for (int ks = 0; ks < 2; ks++) {
      long kf = *(const long*)(Kb + (long long)(nf * 16 + fr) * 64 + ks * 32 + fq * 8);
#pragma unroll
      for (int tf = 0; tf < 4; tf++) s[nf][tf] = mfma8(kf, qf[tf][ks], s[nf][tf]);
    }
  }

  // s_acc = 2*(q.k); true compat = (q.k)/8 -> exp2(s_acc * log2e/16)
  const float CE2 = 0.09016844005556021f;
  u64 mq[4];
#pragma unroll
  for (int tf = 0; tf < 4; tf++)
    mq[tf] = maskbits[((long long)(b * 128) + tt0 + tf * 16 + fr) * 8 + wid];
  float psum[4] = {0.f, 0.f, 0.f, 0.f};
#pragma unroll
  for (int nf = 0; nf < 4; nf++) {
#pragma unroll
    for (int tf = 0; tf < 4; tf++) {
      float pv[4];
#pragma unroll
      for (int q = 0; q < 4; q++) {
        const int bit = nf * 16 + fq * 4 + q;
        float v = exp2f(s[nf][tf][q] * CE2);
        if ((mq[tf] >> bit) & 1ull) v = 0.0f;
        psum[tf] += v;
        pv[q] = v;
      }
      const u32 pw = pk4_fp8(pv[0], pv[1], pv[2], pv[3]);
      const int t = tf * 16 + fr;
      const int o = wstrip + nf * 16 + fq * 4;
      const int s8 = o >> 3, lo = o & 7;
      *(u32*)(Plds + t * 528 + (((s8 ^ (t & 7)) << 3) | lo)) = pw;
    }
  }
#pragma unroll
  for (int tf = 0; tf < 4; tf++) {
    float v = psum[tf];
    v += __shfl_xor(v, 16);
    v += __shfl_xor(v, 32);
    if (lane < 16) rsw[(tf * 16 + lane) * 8 + wid] = v;
  }
  __syncthreads();  // P + rsw visible; V staging drained

  if (tid < 64) {
    float sum = rsw[tid * 8];
#pragma unroll
    for (int ww = 1; ww < 8; ww++) sum += rsw[tid * 8 + ww];
    rst[tid] = __builtin_amdgcn_rcpf(sum);
  }

  const int kkh = wid & 1;
  const int tts = wid >> 1;
  f32x4 o[2];
  o[0] = (f32x4){0.f, 0.f, 0.f, 0.f};
  o[1] = (f32x4){0.f, 0.f, 0.f, 0.f};
  const int tpv = tts * 16 + fr;
#pragma unroll
  for (int nstep = 0; nstep < 16; nstep++) {
    const int s8 = nstep * 4 + fq;
    long pf = *(const long*)(Plds + tpv * 528 + ((s8 ^ (tpv & 7)) << 3));
#pragma unroll
    for (int kf = 0; kf < 2; kf++) {
      const int kk = kkh * 32 + kf * 16 + fr;
      const int vs16 = s8 >> 1, vlo = s8 & 1;
      long vf = *(const long*)(lds + kk * 512 + (((vs16 ^ (kk & 7)) << 4) | (vlo << 3)));
      o[kf] = mfma8(vf, pf, o[kf]);
    }
  }
  __syncthreads();  // rst visible

  const float r4 = rst[tpv] * 4.0f;
  const long long orow = (long long)b * 128 + tt0 + tpv;
#pragma unroll
  for (int kf = 0; kf < 2; kf++) {
    const u32 pw = pk4_fp8(o[kf][0] * r4, o[kf][1] * r4, o[kf][2] * r4, o[kf][3] * r4);
    const int col = h * 64 + kkh * 32 + kf * 16 + fq * 4;
    *(u32*)&o8buf[orow * 512 + col] = pw;
  }
}

// ---------------------------------------------------------------- launch
extern "C" void kernel_launch(void* const* d_in, const int* in_sizes, int n_in,
                              void* d_out, int out_size, void* d_ws, size_t ws_size,
                              hipStream_t stream) {
  (void)in_sizes; (void)n_in; (void)out_size; (void)ws_size;
  const float* emb  = (const float*)d_in[0];
  const int*   cur  = (const int*)d_in[1];
  const float* ucap = (const float*)d_in[2];
  const float* ubat = (const float*)d_in[3];
  const float* ctim = (const float*)d_in[4];
  const void*  mask = d_in[5];
  const float* Wc   = (const float*)d_in[6];
  const float* Wkvl = (const float*)d_in[7];
  const float* Wstep= (const float*)d_in[8];
  const float* Wout = (const float*)d_in[9];

  char* w = (char*)d_ws;
  size_t off = 0;
  auto take = [&](size_t nbytes) -> char* {
    char* p = w + off;
    off += (nbytes + 255) & ~(size_t)255;
    return p;
  };
  unsigned char* maskb = (unsigned char*)take((size_t)256 * 128 * 64);   // 2 MB
  u8* e8               = (u8*)take((size_t)256 * 512 * 512);             // 67 MB fp8 emb
  u8* WkT8             = (u8*)take((size_t)1024 * 512);                  // fp8 x16
  u8* WstepT8          = (u8*)take((size_t)512 * 576);                   // fp8 x16
  u16* W2bf            = (u16*)take((size_t)512 * 512 * 2);
  u16* Woutbf          = (u16*)take((size_t)512 * 512 * 2);
  u8* WfT8             = (u8*)take((size_t)512 * 512);                   // fp8 x64
  float* pmean         = (float*)take((size_t)1024 * 512 * 4);
  float* fixedc        = (float*)take((size_t)256 * 512 * 4);
  u8* K8               = (u8*)take((size_t)256 * 8 * 512 * 64);          // 67 MB
  u8* V8               = (u8*)take((size_t)256 * 8 * 64 * 512);          // 67 MB
  u8* nextn8           = (u8*)take((size_t)32768 * 576);                 // 18.9 MB
  u8* q8               = (u8*)take((size_t)32768 * 512);                 // 16.8 MB
  u8* o8               = (u8*)take((size_t)32768 * 512);                 // 16.8 MB
  u8* tmp8             = (u8*)take((size_t)32768 * 512);                 // 16.8 MB

  maskprep_kernel<<<8192, 256, 0, stream>>>(mask, maskb);
  tcvt8_kernel<<<1024, 256, 0, stream>>>(Wkvl, 1536, 512, 512, WkT8);
  tcvt8_kernel<<<512, 256, 0, stream>>>(Wstep, 512, 515, 576, WstepT8);
  slice_cvt_kernel<<<1024, 256, 0, stream>>>(Wkvl, W2bf);
  cvt_bf_kernel<<<1024, 256, 0, stream>>>(Wout, Woutbf);
  gemm128_plain_kernel<<<16, 256, 0, stream>>>(W2bf, Woutbf, WfT8);
  cvt_pmean_kernel<<<1024, 256, 0, stream>>>(emb, e8, pmean);
  fixedctx_kernel<<<256, 256, 0, stream>>>(pmean, Wc, fixedc);
  build_nextn8_kernel<<<8192, 256, 0, stream>>>(e8, cur, ucap, ubat, ctim, nextn8);

  // KV projection (fp8 datapath, coalesced epilogue)
  gemm_kv8_kernel<<<512, 512, 0, stream>>>(e8, WkT8, K8, V8);
  // q8 = fp8( 2 * (fixedc + nextn8 @ WstepT8 / 16) ), K=576, NT=9
  gemm8_kernel<0><<<512, 512, 0, stream>>>(nextn8, WstepT8, 576, 576, 9, q8, fixedc);
  // attention v5 (fp8): block = (b, h, t-half)
  attn_kernel<<<4096, 512, 0, stream>>>(q8, K8, V8, (const u64*)maskb, o8);
  // tmp8 = fp8( (o8 @ WfT8) / 32 ) = 8 * true, K=512, NT=8
  gemm8_kernel<1><<<512, 512, 0, stream>>>(o8, WfT8, 512, 512, 8, tmp8, nullptr);
  // logits (fp8 GEMM) + tanh/mask + log-softmax fused -> f32 d_out
  gemm_lsm8_kernel<<<512, 512, 0, stream>>>(e8, tmp8, (const u64*)maskb, (float*)d_out);
}

// Round 19
// 451.430 us; speedup vs baseline: 1.0359x; 1.0091x over previous
//
#include <hip/hip_runtime.h>
#include <hip/hip_bf16.h>
#include <hip/hip_fp8.h>
#include <stdint.h>

typedef unsigned char  u8;
typedef unsigned short u16;
typedef unsigned int   u32;
typedef unsigned long long u64;
typedef __attribute__((ext_vector_type(4))) float f32x4;
typedef __attribute__((ext_vector_type(4))) unsigned int u32x4;
typedef __attribute__((ext_vector_type(8))) short s16x8;

#define NEG_INF (-1e9f)

__device__ __forceinline__ u16 f2bf(float f) {
  __hip_bfloat16 h = __float2bfloat16(f);
  return __builtin_bit_cast(u16, h);
}

__device__ __forceinline__ u8 f2fp8(float f) {
  __hip_fp8_e4m3 h(f);
  return (u8)h.__x;
}

// HW packed fp32->fp8 conversion (OCP on gfx950); safe fallback if absent.
#if defined(__has_builtin)
#if __has_builtin(__builtin_amdgcn_cvt_pk_fp8_f32)
#define HAVE_PK8 1
#endif
#endif

__device__ __forceinline__ u32 pk4_fp8(float a, float b, float c, float d) {
#ifdef HAVE_PK8
  int r = __builtin_amdgcn_cvt_pk_fp8_f32(a, b, 0, false);
  r = __builtin_amdgcn_cvt_pk_fp8_f32(c, d, r, true);
  return (u32)r;
#else
  return (u32)f2fp8(a) | ((u32)f2fp8(b) << 8) | ((u32)f2fp8(c) << 16) |
         ((u32)f2fp8(d) << 24);
#endif
}

__device__ __forceinline__ f32x4 mfma16(s16x8 a, s16x8 b, f32x4 c) {
  return __builtin_amdgcn_mfma_f32_16x16x32_bf16(a, b, c, 0, 0, 0);
}

__device__ __forceinline__ f32x4 mfma8(long a, long b, f32x4 c) {
  return __builtin_amdgcn_mfma_f32_16x16x32_fp8_fp8(a, b, c, 0, 0, 0);
}

// async global->LDS, 16 B per lane; LDS dest is wave-uniform base + lane*16
#define GLOAD16(g, l)                                                        \
  __builtin_amdgcn_global_load_lds(                                          \
      (const __attribute__((address_space(1))) unsigned int*)(g),            \
      (__attribute__((address_space(3))) unsigned int*)(l), 16, 0, 0)
// width-4 variant; LDS dest = base + lane*4
#define GLOAD4(g, l)                                                         \
  __builtin_amdgcn_global_load_lds(                                          \
      (const __attribute__((address_space(1))) unsigned int*)(g),            \
      (__attribute__((address_space(3))) unsigned int*)(l), 4, 0, 0)

#define WAITV(n) asm volatile("s_waitcnt vmcnt(" #n ")" ::: "memory")
#define WAITLGKM asm volatile("s_waitcnt lgkmcnt(0)" ::: "memory")
#define SBAR __builtin_amdgcn_sched_barrier(0)
#define HBAR __builtin_amdgcn_s_barrier()

// ------------------------------------------- mask prep (fused dtype detect)
__global__ __launch_bounds__(256) void maskprep_kernel(const void* __restrict__ mraw,
                                                       unsigned char* __restrict__ mb) {
  __shared__ int anyS;
  const int tid = threadIdx.x;
  int loc = 0;
  {
    u32 v = ((const u32*)mraw)[tid];
    if (v & 0xFFFFFF00u) loc = 1;  // int32 0/1 never sets high bytes
  }
  if (tid == 0) anyS = 0;
  __syncthreads();
  if (loc) atomicOr(&anyS, 1);
  __syncthreads();
  const int is1byte = anyS;

  long long idx = (long long)blockIdx.x * 256 + tid;  // B*T*64 = 2097152
  long long bt = idx >> 6;
  int ch = (int)(idx & 63);
  unsigned char byte = 0;
  if (is1byte) {
    u64 v = *(const u64*)((const unsigned char*)mraw + bt * 512 + ch * 8);
#pragma unroll
    for (int i = 0; i < 8; i++)
      if ((v >> (8 * i)) & 0xFFull) byte |= (unsigned char)(1 << i);
  } else {
    const int* p = (const int*)mraw + bt * 512 + ch * 8;
#pragma unroll
    for (int i = 0; i < 8; i++)
      if (p[i]) byte |= (unsigned char)(1 << i);
  }
  mb[idx] = byte;
}

// ---------------------------------------------------------------- weight prep
// merged transpose-cvt for both fp8 weights (grid 1536)
__global__ void tcvt8both_kernel(const float* __restrict__ Wkvl,
                                 const float* __restrict__ Wstep,
                                 u8* __restrict__ WkT8, u8* __restrict__ WstepT8) {
  if (blockIdx.x < 1024) {
    const int i = blockIdx.x;  // WkT8[i][j] = fp8(Wkvl[j][i] * 16)
    for (int j = threadIdx.x; j < 512; j += 256)
      WkT8[(long long)i * 512 + j] = f2fp8(Wkvl[(long long)j * 1536 + i] * 16.0f);
  } else {
    const int i = blockIdx.x - 1024;  // WstepT8[i][j] = fp8(Wstep[j][i] * 16), pad 515..575
    for (int j = threadIdx.x; j < 576; j += 256) {
      float v = (j < 515) ? Wstep[(long long)j * 512 + i] * 16.0f : 0.0f;
      WstepT8[(long long)i * 576 + j] = f2fp8(v);
    }
  }
}

// merged bf16 weight conversions (grid 2048): W2bf slice + Woutbf copy
__global__ void wcvt_kernel(const float* __restrict__ Wkvl,
                            const float* __restrict__ Wout,
                            u16* __restrict__ W2bf, u16* __restrict__ Woutbf) {
  long long idx = (long long)blockIdx.x * 256 + threadIdx.x;  // 0..524287
  if (idx < 262144) {
    long long dd = idx >> 9;
    int hh = (int)(idx & 511);
    W2bf[idx] = f2bf(Wkvl[dd * 1536 + 1024 + hh]);
  } else {
    long long j = idx - 262144;
    Woutbf[j] = f2bf(Wout[j]);
  }
}

// ---------------- emb fp32 -> fp8 + partial mean (fused)
__global__ __launch_bounds__(256) void cvt_pmean_kernel(const float* __restrict__ emb,
                                                        u8* __restrict__ e8,
                                                        float* __restrict__ pmean) {
  const int bq = blockIdx.x >> 2, nq = blockIdx.x & 3;
  const int tid = threadIdx.x;
  const int ro = tid >> 7;
  const int c4 = (tid & 127) << 2;
  const long long base = ((long long)bq * 512 + nq * 128) * 512;
  float s[4] = {0.f, 0.f, 0.f, 0.f};
  for (int n = ro; n < 128; n += 2) {
    f32x4 v = *(const f32x4*)&emb[base + (long long)n * 512 + c4];
#pragma unroll
    for (int i = 0; i < 4; i++) s[i] += v[i];
    *(u32*)&e8[base + (long long)n * 512 + c4] = pk4_fp8(v[0], v[1], v[2], v[3]);
  }
  __shared__ float ls[2][512];
#pragma unroll
  for (int i = 0; i < 4; i++) ls[ro][c4 + i] = s[i];
  __syncthreads();
  float* dst = pmean + (long long)blockIdx.x * 512;
  dst[tid] = ls[0][tid] + ls[1][tid];
  dst[tid + 256] = ls[0][tid + 256] + ls[1][tid + 256];
}

__global__ __launch_bounds__(256) void fixedctx_kernel(const float* __restrict__ pmean,
                                                       const float* __restrict__ Wc,
                                                       float* __restrict__ fixedc) {
  __shared__ float mf[512];
  int b = blockIdx.x;
  const float* p = pmean + (long long)b * 4 * 512;
  for (int d = threadIdx.x; d < 512; d += 256)
    mf[d] = (p[d] + p[512 + d] + p[1024 + d] + p[1536 + d]) * (1.0f / 512.0f);
  __syncthreads();
  for (int h = threadIdx.x; h < 512; h += 256) {
    float s0 = 0.f, s1 = 0.f, s2 = 0.f, s3 = 0.f;  // 4-way chain break
    for (int d = 0; d < 512; d += 4) {
      s0 += mf[d + 0] * Wc[(long long)(d + 0) * 512 + h];
      s1 += mf[d + 1] * Wc[(long long)(d + 1) * 512 + h];
      s2 += mf[d + 2] * Wc[(long long)(d + 2) * 512 + h];
      s3 += mf[d + 3] * Wc[(long long)(d + 3) * 512 + h];
    }
    fixedc[(long long)b * 512 + h] = (s0 + s1) + (s2 + s3);
  }
}

// -------------------------------- next-node features, fp8 (gather from e8, ld 576)
__global__ __launch_bounds__(256) void build_nextn8_kernel(
    const u8* __restrict__ e8, const int* __restrict__ cur,
    const float* __restrict__ ucap, const float* __restrict__ ubat,
    const float* __restrict__ ctim, u8* __restrict__ outp) {
  const long long rowm = (long long)blockIdx.x * 4 + (threadIdx.x >> 6);
  const int lane = threadIdx.x & 63;
  const int b = (int)(rowm >> 7);
  const int node = cur[rowm];
  const u8* src = e8 + ((long long)b * 512 + node) * 512;
  u8* dst = outp + rowm * 576;
  *(u64*)&dst[lane * 8] = *(const u64*)&src[lane * 8];
  if (lane < 8) {
    u64 v = 0;
    if (lane == 0) {
      v = (u64)f2fp8(1.0f - ucap[rowm]) | ((u64)f2fp8(1.0f - ubat[rowm]) << 8) |
          ((u64)f2fp8(ctim[rowm]) << 16);
    }
    *(u64*)&dst[512 + lane * 8] = v;
  }
}

// =============================================================================
// KV projection GEMM (fp8, coalesced epilogue) — round-16 form (2-deep, 57.3 KB)
// =============================================================================
__global__ __launch_bounds__(512, 4) void gemm_kv8_kernel(
    const u8* __restrict__ A8, const u8* __restrict__ Bw8,
    u8* __restrict__ K8, u8* __restrict__ V8) {
  __shared__ __align__(16) char lds[57344];  // 48 KB stage + 8 KB epilogue tiles
  const int tid = threadIdx.x;
  const int lane = tid & 63;
  const int wid = tid >> 6;
  const int wr = wid >> 1, wc = wid & 1;  // 4M x 2N
  const int fr = lane & 15;
  const int fq = lane >> 4;

  const int p = blockIdx.x;   // 512 blocks, 64/XCD
  const int x = p & 7;
  const int i = p >> 3;       // 0..63
  const int ntile = i & 7;    // N = 1024 / 128
  const int mgrp = i >> 3;    // 0..7
  const long long nrow0 = (long long)ntile * 128;

  const int srow = tid >> 2;  // 0..127 staging row
  const int sc = tid & 3;     // 16B chunk

#define MROW(tt2) (((long long)x * 64 + mgrp * 8 + ((tt2) >> 3)) * 256)
#define KOF(tt2) (((tt2) & 7) * 64)

#define STAGEA(dd, tt2)                                                       \
  {                                                                           \
    _Pragma("unroll") for (int g_ = 0; g_ < 2; g_++) {                        \
      const int r_ = g_ * 128 + srow;                                         \
      GLOAD16(A8 + (MROW(tt2) + r_) * 512ll + KOF(tt2) +                      \
                  ((sc ^ ((r_ >> 1) & 3)) << 4),                              \
              lds + (dd) * 24576 + g_ * 8192 + wid * 1024);                   \
    }                                                                         \
  }
#define STAGEB(dd, tt2)                                                       \
  {                                                                           \
    GLOAD16(Bw8 + (nrow0 + srow) * 512ll + KOF(tt2) +                         \
                ((sc ^ ((srow >> 1) & 3)) << 4),                              \
            lds + (dd) * 24576 + 16384 + wid * 1024);                         \
  }

#define READ_A(dst, mb)                                                       \
  _Pragma("unroll") for (int ks = 0; ks < 2; ks++) {                          \
    const int r_ = wr * 64 + (mb) * 16 + fr;                                  \
    dst[ks] = *(const long*)(ab + r_ * 64 + (((ks * 4 + fq) ^ (r_ & 6)) << 3)); \
  }
#define MFMA_PH(src, mb)                                                      \
  _Pragma("unroll") for (int nb = 0; nb < 4; nb++)                            \
  _Pragma("unroll") for (int ks = 0; ks < 2; ks++)                            \
    acc[mb][nb] = mfma8(src[ks], bfrag[nb][ks], acc[mb][nb]);

  STAGEB(0, 0); STAGEA(0, 0);
  STAGEB(1, 1); STAGEA(1, 1);

  f32x4 acc[4][4];
  char* tile = lds + 49152 + wid * 1024;
  const int hh = (ntile * 2 + wc) & 7;

#pragma unroll 1
  for (int u = 0; u < 8; u++) {
#pragma unroll
    for (int ii = 0; ii < 4; ii++)
#pragma unroll
      for (int jj = 0; jj < 4; jj++) acc[ii][jj] = (f32x4){0.f, 0.f, 0.f, 0.f};

#pragma unroll 1
    for (int t8 = 0; t8 < 8; t8++) {
      const int tt = u * 8 + t8;
      const int d = tt & 1;
      if (tt == 63) { WAITV(0); } else { WAITV(3); }
      HBAR; SBAR;

      const char* ab = lds + d * 24576;
      const char* bb = lds + d * 24576 + 16384;

      long bfrag[4][2];
#pragma unroll
      for (int nb = 0; nb < 4; nb++)
#pragma unroll
        for (int ks = 0; ks < 2; ks++) {
          const int brow = wc * 64 + nb * 16 + fr;
          bfrag[nb][ks] =
              *(const long*)(bb + brow * 64 + (((ks * 4 + fq) ^ (brow & 6)) << 3));
        }
      long afA[2], afB[2];
      READ_A(afA, 0);
      WAITLGKM; SBAR;
      READ_A(afB, 1);
      __builtin_amdgcn_s_setprio(1);
      MFMA_PH(afA, 0);
      __builtin_amdgcn_s_setprio(0);
      WAITLGKM; SBAR;
      READ_A(afA, 2);
      __builtin_amdgcn_s_setprio(1);
      MFMA_PH(afB, 1);
      __builtin_amdgcn_s_setprio(0);
      WAITLGKM; SBAR;
      READ_A(afB, 3);
      __builtin_amdgcn_s_setprio(1);
      MFMA_PH(afA, 2);
      __builtin_amdgcn_s_setprio(0);
      WAITLGKM; SBAR;
      HBAR;
      if (tt + 2 < 64) { STAGEB(d, tt + 2); STAGEA(d, tt + 2); }
      __builtin_amdgcn_s_setprio(1);
      MFMA_PH(afB, 3);
      __builtin_amdgcn_s_setprio(0);
    }

    // ---- coalesced epilogue via per-wave LDS transpose tile ----
    const long long mrow0 = MROW(u * 8);
    const int bbx = (int)(mrow0 >> 9);
    const int nodeb = (int)(mrow0 & 511);
    const long long bhoff = ((long long)(bbx * 8 + hh)) << 15;

    if (ntile < 4) {
      // K path: tile logical [16 node][64 kk] bytes, dword-XOR swizzled
#pragma unroll
      for (int mb = 0; mb < 4; mb++) {
#pragma unroll
        for (int nb = 0; nb < 4; nb++) {
          const u32 pw = pk4_fp8(acc[mb][nb][0] * 0.0625f, acc[mb][nb][1] * 0.0625f,
                                 acc[mb][nb][2] * 0.0625f, acc[mb][nb][3] * 0.0625f);
          const int colhi = (nb * 16 + (fr & ~3));
          const int collo = fr & 3;
#pragma unroll
          for (int q = 0; q < 4; q++) {
            const int row = fq * 4 + q;
            tile[row * 64 + (colhi ^ ((row & 15) << 2)) + collo] = (u8)(pw >> (8 * q));
          }
        }
        WAITLGKM; SBAR;
        const int row = lane >> 2;
        u32x4 val;
#pragma unroll
        for (int j = 0; j < 4; j++) {
          const int dw = ((lane & 3) * 4 + j) << 2;
          val[j] = *(const u32*)(tile + row * 64 + (dw ^ ((row & 15) << 2)));
        }
        WAITLGKM; SBAR;
        u8* dst = K8 + bhoff + (long long)(nodeb + wr * 64 + mb * 16) * 64;
        *(u32x4*)(dst + lane * 16) = val;
      }
    } else {
      // V path: tile [64 kk][16 node] bytes; u32 writes along node.
#pragma unroll
      for (int mb = 0; mb < 4; mb++) {
#pragma unroll
        for (int nb = 0; nb < 4; nb++) {
          const u32 pw = pk4_fp8(acc[mb][nb][0] * 0.0625f, acc[mb][nb][1] * 0.0625f,
                                 acc[mb][nb][2] * 0.0625f, acc[mb][nb][3] * 0.0625f);
          *(u32*)(tile + (nb * 16 + fr) * 16 + fq * 4) = pw;
        }
        WAITLGKM; SBAR;
        u32x4 val = *(const u32x4*)(tile + lane * 16);  // kk = lane
        WAITLGKM; SBAR;
        const int ngrp = (nodeb + wr * 64 + mb * 16) >> 4;
        u8* dst = V8 + bhoff + (long long)ngrp * 1024;
        *(u32x4*)(dst + lane * 16) = val;
      }
    }
  }
#undef STAGEA
#undef STAGEB
#undef READ_A
#undef MFMA_PH
#undef MROW
#undef KOF
}

// =============================================================================
// gemm8: generic fp8 GEMM
// MODE 0 (query): out = fp8( (acc/16 + fixedc[b][col]) * 2 )   [q8 = 2q]
// MODE 1 (tmp):   out = fp8( acc / 32 )                        [tmp8 = 8*true]
// =============================================================================
template <int MODE>
__global__ __launch_bounds__(512, 4) void gemm8_kernel(
    const u8* __restrict__ A8, const u8* __restrict__ B8,
    int ldA, int ldB, int NT,
    u8* __restrict__ out0, const float* __restrict__ aux) {
  __shared__ __align__(16) char lds[49152];
  const int tid = threadIdx.x;
  const int lane = tid & 63;
  const int wid = tid >> 6;
  const int wr = wid >> 1, wc = wid & 1;
  const int fr = lane & 15;
  const int fq = lane >> 4;

  const int p = blockIdx.x;          // 512
  const int wk = (p & 7) * 64 + (p >> 3);
  const int mtile = wk >> 2;
  const int ntile = wk & 3;
  const long long mrow0 = (long long)mtile * 256;
  const long long nrow0 = (long long)ntile * 128;

  const int srow = tid >> 2;
  const int sc = tid & 3;

#define STAGEA8(dd, k0)                                                       \
  {                                                                           \
    _Pragma("unroll") for (int g_ = 0; g_ < 2; g_++) {                        \
      const int r_ = g_ * 128 + srow;                                         \
      GLOAD16(A8 + (mrow0 + r_) * (long long)ldA + (k0) +                     \
                  ((sc ^ ((r_ >> 1) & 3)) << 4),                              \
              lds + (dd) * 24576 + g_ * 8192 + wid * 1024);                   \
    }                                                                         \
  }
#define STAGEB8(dd, k0)                                                       \
  {                                                                           \
    GLOAD16(B8 + (nrow0 + srow) * (long long)ldB + (k0) +                     \
                ((sc ^ ((srow >> 1) & 3)) << 4),                              \
            lds + (dd) * 24576 + 16384 + wid * 1024);                         \
  }
#define READ_A8(dst, mb)                                                      \
  _Pragma("unroll") for (int ks = 0; ks < 2; ks++) {                          \
    const int r_ = wr * 64 + (mb) * 16 + fr;                                  \
    dst[ks] = *(const long*)(ab + r_ * 64 + (((ks * 4 + fq) ^ (r_ & 6)) << 3)); \
  }
#define MFMA_PH8(src, mb)                                                     \
  _Pragma("unroll") for (int nb = 0; nb < 4; nb++)                            \
  _Pragma("unroll") for (int ks = 0; ks < 2; ks++)                            \
    acc[mb][nb] = mfma8(src[ks], bfrag[nb][ks], acc[mb][nb]);

  f32x4 acc[4][4];
#pragma unroll
  for (int ii = 0; ii < 4; ii++)
#pragma unroll
    for (int jj = 0; jj < 4; jj++) acc[ii][jj] = (f32x4){0.f, 0.f, 0.f, 0.f};

  STAGEB8(0, 0); STAGEA8(0, 0);
  STAGEB8(1, 64); STAGEA8(1, 64);

#pragma unroll 1
  for (int t = 0; t < NT; t++) {
    const int d = t & 1;
    if (t == NT - 1) { WAITV(0); } else { WAITV(3); }
    HBAR; SBAR;

    const char* ab = lds + d * 24576;
    const char* bb = lds + d * 24576 + 16384;

    long bfrag[4][2];
#pragma unroll
    for (int nb = 0; nb < 4; nb++)
#pragma unroll
      for (int ks = 0; ks < 2; ks++) {
        const int brow = wc * 64 + nb * 16 + fr;
        bfrag[nb][ks] =
            *(const long*)(bb + brow * 64 + (((ks * 4 + fq) ^ (brow & 6)) << 3));
      }
    long afA[2], afB[2];
    READ_A8(afA, 0);
    WAITLGKM; SBAR;
    READ_A8(afB, 1);
    __builtin_amdgcn_s_setprio(1);
    MFMA_PH8(afA, 0);
    __builtin_amdgcn_s_setprio(0);
    WAITLGKM; SBAR;
    READ_A8(afA, 2);
    __builtin_amdgcn_s_setprio(1);
    MFMA_PH8(afB, 1);
    __builtin_amdgcn_s_setprio(0);
    WAITLGKM; SBAR;
    READ_A8(afB, 3);
    __builtin_amdgcn_s_setprio(1);
    MFMA_PH8(afA, 2);
    __builtin_amdgcn_s_setprio(0);
    WAITLGKM; SBAR;
    HBAR;
    if (t + 2 < NT) { STAGEB8(d, (t + 2) * 64); STAGEA8(d, (t + 2) * 64); }
    __builtin_amdgcn_s_setprio(1);
    MFMA_PH8(afB, 3);
    __builtin_amdgcn_s_setprio(0);
  }
#undef STAGEA8
#undef STAGEB8
#undef READ_A8
#undef MFMA_PH8

  const int colbase = (int)(ntile * 128) + wc * 64;
#pragma unroll
  for (int mb = 0; mb < 4; mb++) {
    const long long row0 = mrow0 + wr * 64 + mb * 16 + fq * 4;
#pragma unroll
    for (int nb = 0; nb < 4; nb++) {
      const int col = colbase + nb * 16 + fr;
      u32 pw;
      if (MODE == 0) {
        float v0 = acc[mb][nb][0] * 0.0625f + aux[((row0 + 0) >> 7) * 512 + col];
        float v1 = acc[mb][nb][1] * 0.0625f + aux[((row0 + 1) >> 7) * 512 + col];
        float v2 = acc[mb][nb][2] * 0.0625f + aux[((row0 + 2) >> 7) * 512 + col];
        float v3 = acc[mb][nb][3] * 0.0625f + aux[((row0 + 3) >> 7) * 512 + col];
        pw = pk4_fp8(v0 * 2.0f, v1 * 2.0f, v2 * 2.0f, v3 * 2.0f);
      } else {
        pw = pk4_fp8(acc[mb][nb][0] * 0.03125f, acc[mb][nb][1] * 0.03125f,
                     acc[mb][nb][2] * 0.03125f, acc[mb][nb][3] * 0.03125f);
      }
#pragma unroll
      for (int q = 0; q < 4; q++)
        out0[(row0 + q) * 512 + col] = (u8)(pw >> (8 * q));
    }
  }
}

// =============================================================================
// gemm_lsm8
// =============================================================================
__global__ __launch_bounds__(512, 4) void gemm_lsm8_kernel(
    const u8* __restrict__ e8, const u8* __restrict__ tmp8,
    const u64* __restrict__ maskb, float* __restrict__ outp) {
  __shared__ __align__(16) char lds[73728];
  const int tid = threadIdx.x;
  const int lane = tid & 63;
  const int wid = tid >> 6;
  const int fr = lane & 15;
  const int fq = lane >> 4;

  const int p = blockIdx.x;           // 512 blocks
  const int x = p & 7;
  const int i = p >> 3;               // 0..63
  const int thalf = i & 1;
  const int b = x * 32 + (i >> 1);

  const u8* Ab = e8 + (long long)b * 262144;
  const u8* Bb = tmp8 + (long long)b * 65536 + (long long)thalf * 64 * 512;

  const int srow = tid >> 2;  // 0..127
  const int sc = tid & 3;

#define STAGEA(dd, k0)                                                        \
  {                                                                           \
    _Pragma("unroll") for (int g_ = 0; g_ < 4; g_++) {                        \
      const int r_ = g_ * 128 + srow;                                         \
      GLOAD16(Ab + r_ * 512ll + (k0) + ((sc ^ ((r_ >> 1) & 3)) << 4),         \
              lds + (dd) * 32768 + g_ * 8192 + wid * 1024);                   \
    }                                                                         \
  }
#define STAGEB(dd, k0)                                                        \
  {                                                                           \
    _Pragma("unroll") for (int g_ = 0; g_ < 2; g_++) {                        \
      const int r_ = g_ * 32 + (tid >> 4);                                    \
      const int lb_ = (tid & 15) * 4;                                         \
      const int gb_ = ((((lb_ >> 4) ^ ((r_ >> 1) & 3))) << 4) | (lb_ & 15);   \
      GLOAD4(Bb + r_ * 512ll + (k0) + gb_,                                    \
             lds + 65536 + (dd) * 4096 + g_ * 2048 + wid * 256);              \
    }                                                                         \
  }
#define READ_A(dst, mb)                                                       \
  _Pragma("unroll") for (int ks = 0; ks < 2; ks++) {                          \
    const int r_ = wid * 64 + (mb) * 16 + fr;                                 \
    dst[ks] = *(const long*)(ab + r_ * 64 + (((ks * 4 + fq) ^ (r_ & 6)) << 3)); \
  }
#define MFMA_PH(src, mb)                                                      \
  _Pragma("unroll") for (int nb = 0; nb < 4; nb++)                            \
  _Pragma("unroll") for (int ks = 0; ks < 2; ks++)                            \
    acc[mb][nb] = mfma8(src[ks], bfrag[nb][ks], acc[mb][nb]);

  f32x4 acc[4][4];
#pragma unroll
  for (int ii = 0; ii < 4; ii++)
#pragma unroll
    for (int jj = 0; jj < 4; jj++) acc[ii][jj] = (f32x4){0.f, 0.f, 0.f, 0.f};

  STAGEB(0, 0); STAGEA(0, 0);
  STAGEB(1, 64); STAGEA(1, 64);

#pragma unroll 1
  for (int t = 0; t < 8; t++) {
    const int d = t & 1;
    if (t == 7) { WAITV(0); } else { WAITV(6); }
    HBAR; SBAR;

    const char* ab = lds + d * 32768;
    const char* bb = lds + 65536 + d * 4096;

    long bfrag[4][2];
#pragma unroll
    for (int nb = 0; nb < 4; nb++)
#pragma unroll
      for (int ks = 0; ks < 2; ks++) {
        const int brow = nb * 16 + fr;
        bfrag[nb][ks] =
            *(const long*)(bb + brow * 64 + (((ks * 4 + fq) ^ (brow & 6)) << 3));
      }
    long afA[2], afB[2];
    READ_A(afA, 0);
    WAITLGKM; SBAR;
    READ_A(afB, 1);
    __builtin_amdgcn_s_setprio(1);
    MFMA_PH(afA, 0);
    __builtin_amdgcn_s_setprio(0);
    WAITLGKM; SBAR;
    READ_A(afA, 2);
    __builtin_amdgcn_s_setprio(1);
    MFMA_PH(afB, 1);
    __builtin_amdgcn_s_setprio(0);
    WAITLGKM; SBAR;
    READ_A(afB, 3);
    __builtin_amdgcn_s_setprio(1);
    MFMA_PH(afA, 2);
    __builtin_amdgcn_s_setprio(0);
    WAITLGKM; SBAR;
    HBAR;
    if (t + 2 < 8) { STAGEB(d, (t + 2) * 64); STAGEA(d, (t + 2) * 64); }
    __builtin_amdgcn_s_setprio(1);
    MFMA_PH(afB, 3);
    __builtin_amdgcn_s_setprio(0);
  }
#undef STAGEA
#undef STAGEB
#undef READ_A
#undef MFMA_PH

  // ---- fused tanh/mask + log-softmax epilogue (acc = 8 * true logits-dot)
  float* red = (float*)lds;
  const float rs8 = 0.044194173824159216f * 0.125f;  // 1/sqrt(512)/8
  const float L2E = 1.4426950408889634f;

  float lmax[4];
#pragma unroll
  for (int nb = 0; nb < 4; nb++) {
    const int tl = nb * 16 + fr;
    const long long orow = (long long)b * 128 + thalf * 64 + tl;
    const u64 w = maskb[orow * 8 + wid];
    float mx = -3.0e38f;
#pragma unroll
    for (int mb = 0; mb < 4; mb++) {
      f32x4 r;
#pragma unroll
      for (int q = 0; q < 4; q++) {
        float xv = acc[mb][nb][q] * rs8;
        float e = exp2f(xv * 2.8853900817779268f);  // e^{2x}
        float th = 1.0f - 2.0f * __builtin_amdgcn_rcpf(e + 1.0f);
        float lg = 10.0f * th;
        const int bitn = mb * 16 + fq * 4 + q;
        if ((w >> bitn) & 1ull) lg = NEG_INF;
        r[q] = lg;
        mx = fmaxf(mx, lg);
      }
      acc[mb][nb] = r;
    }
    mx = fmaxf(mx, __shfl_xor(mx, 16));
    mx = fmaxf(mx, __shfl_xor(mx, 32));
    lmax[nb] = mx;
  }
  __syncthreads();
  if (lane < 16) {
#pragma unroll
    for (int nb = 0; nb < 4; nb++) red[wid * 64 + nb * 16 + lane] = lmax[nb];
  }
  __syncthreads();
  if (tid < 64) {
    float m = red[tid];
#pragma unroll
    for (int ww = 1; ww < 8; ww++) m = fmaxf(m, red[ww * 64 + tid]);
    red[512 + tid] = m;
  }
  __syncthreads();
  float lsum[4];
#pragma unroll
  for (int nb = 0; nb < 4; nb++) {
    const float m = red[512 + nb * 16 + fr];
    float s = 0.f;
#pragma unroll
    for (int mb = 0; mb < 4; mb++)
#pragma unroll
      for (int q = 0; q < 4; q++) s += exp2f((acc[mb][nb][q] - m) * L2E);
    s += __shfl_xor(s, 16);
    s += __shfl_xor(s, 32);
    lsum[nb] = s;
  }
  if (lane < 16) {
#pragma unroll
    for (int nb = 0; nb < 4; nb++) red[576 + wid * 64 + nb * 16 + lane] = lsum[nb];
  }
  __syncthreads();
  if (tid < 64) {
    float s = red[576 + tid];
#pragma unroll
    for (int ww = 1; ww < 8; ww++) s += red[576 + ww * 64 + tid];
    red[1088 + tid] = red[512 + tid] + logf(s);
  }
  __syncthreads();
#pragma unroll
  for (int nb = 0; nb < 4; nb++) {
    const int tl = nb * 16 + fr;
    const long long orow = (long long)b * 128 + thalf * 64 + tl;
    const float lse = red[1088 + tl];
#pragma unroll
    for (int mb = 0; mb < 4; mb++) {
      const int node0 = wid * 64 + mb * 16 + fq * 4;
      f32x4 r = acc[mb][nb];
#pragma unroll
      for (int q = 0; q < 4; q++) r[q] -= lse;
      *(f32x4*)&outp[orow * 512 + node0] = r;
    }
  }
}

// ---------------- small 128^2 GEMM (used once for WfT8 = fp8(WfT x 64))
__global__ __launch_bounds__(256) void gemm128_plain_kernel(
    const u16* __restrict__ A, const u16* __restrict__ Bv, u8* __restrict__ outp) {
  __shared__ u16 lA[128 * 32];
  __shared__ u16 lB[128 * 32];
  const int tid = threadIdx.x;
  const int lane = tid & 63;
  const int wave = tid >> 6;
  const int wr = wave >> 1, wc = wave & 1;

  const int p = blockIdx.x;  // grid 16
  const int wk = (p & 7) * 2 + (p >> 3);
  const int ntile = wk & 3;
  const int mtile = wk >> 2;
  const long long arow0 = (long long)mtile * 128;
  const long long brow0 = (long long)ntile * 128;

  f32x4 acc[4][4];
#pragma unroll
  for (int i = 0; i < 4; i++)
#pragma unroll
    for (int j = 0; j < 4; j++) acc[i][j] = (f32x4){0.f, 0.f, 0.f, 0.f};

  const int sc8 = (lane & 3) << 3;

  for (int k0 = 0; k0 < 512; k0 += 32) {
    __syncthreads();
#pragma unroll
    for (int i = 0; i < 2; i++) {
      GLOAD16(A + (arow0 + i * 64 + wave * 16 + (lane >> 2)) * 512ll + k0 + sc8,
              &lA[(i * 64 + wave * 16) * 32]);
      GLOAD16(Bv + (brow0 + i * 64 + wave * 16 + (lane >> 2)) * 512ll + k0 + sc8,
              &lB[(i * 64 + wave * 16) * 32]);
    }
    __syncthreads();
    s16x8 af[4], bfr[4];
#pragma unroll
    for (int i = 0; i < 4; i++)
      af[i] = *(const s16x8*)&lA[(wr * 64 + i * 16 + (lane & 15)) * 32 + ((lane >> 4) << 3)];
#pragma unroll
    for (int j = 0; j < 4; j++)
      bfr[j] = *(const s16x8*)&lB[(wc * 64 + j * 16 + (lane & 15)) * 32 + ((lane >> 4) << 3)];
#pragma unroll
    for (int i = 0; i < 4; i++)
#pragma unroll
      for (int j = 0; j < 4; j++) acc[i][j] = mfma16(af[i], bfr[j], acc[i][j]);
  }

#pragma unroll
  for (int i = 0; i < 4; i++) {
    const int rl = wr * 64 + i * 16 + ((lane >> 4) << 2);
#pragma unroll
    for (int j = 0; j < 4; j++) {
      const int cl = wc * 64 + j * 16 + (lane & 15);
#pragma unroll
      for (int q = 0; q < 4; q++)
        outp[(arow0 + rl + q) * 512 + brow0 + cl] = f2fp8(acc[i][j][q] * 64.0f);
    }
  }
}

// =============================================================================
// Fused attention v5 (fp8 end-to-end) — round-16 form.
// Block = (b, h, t-half). 4096 blocks x 512 threads.
// =============================================================================
__global__ __launch_bounds__(512, 4) void attn_kernel(
    const u8* __restrict__ q8, const u8* __restrict__ K8,
    const u8* __restrict__ V8, const u64* __restrict__ maskbits,
    u8* __restrict__ o8buf) {
  __shared__ __align__(16) char lds[68864];
  char* Plds = lds + 32768;
  float* rsw = (float*)(lds + 66560);
  float* rst = (float*)(lds + 68608);

  const int p = blockIdx.x;           // 4096 blocks, 512/XCD
  const int fb = (p & 7) * 512 + (p >> 3);
  const int thalf = fb & 1;
  const int h = (fb >> 1) & 7;
  const int b = fb >> 4;
  const int bh = b * 8 + h;
  const int tid = threadIdx.x;
  const int lane = tid & 63;
  const int wid = tid >> 6;
  const int fr = lane & 15;
  const int fq = lane >> 4;
  const int tt0 = thalf * 64;

  // ---- stage V^T fp8 once; source = chunk layout, dest linear (wave-uniform)
  {
    const u8* Vb = V8 + (long long)bh * 32768;
#pragma unroll
    for (int it = 0; it < 4; it++) {
      const int Lc = it * 512 + wid * 64 + lane;  // LDS 16B-chunk index
      const int kk = Lc >> 5;
      const int s16p = Lc & 31;
      const int s16 = s16p ^ (kk & 7);            // logical node-group
      GLOAD16(Vb + (s16 * 64 + kk) * 16, lds + (it * 512 + wid * 64) * 16);
    }
  }

  const u8* Qb = q8 + ((long long)(b * 128 + tt0)) * 512 + h * 64;
  long qf[4][2];
#pragma unroll
  for (int tf = 0; tf < 4; tf++)
#pragma unroll
    for (int ks = 0; ks < 2; ks++)
      qf[tf][ks] = *(const long*)(Qb + (long long)(tf * 16 + fr) * 512 + ks * 32 + fq * 8);

  const int wstrip = wid * 64;
  const u8* Kb = K8 + ((long long)bh * 512 + wstrip) * 64;
  f32x4 s[4][4];
#pragma unroll
  for (int nf = 0; nf < 4; nf++)
#pragma unroll
    for (int tf = 0; tf < 4; tf++) s[nf][tf] = (f32x4){0.f, 0.f, 0.f, 0.f};
#pragma unroll
  for (int nf = 0; nf < 4; nf++) {
#pragma unroll
    for (int ks = 0; ks < 2; ks++) {
      long kf = *(const long*)(Kb + (long long)(nf * 16 + fr) * 64 + ks * 32 + fq * 8);
#pragma unroll
      for (int tf = 0; tf < 4; tf++) s[nf][tf] = mfma8(kf, qf[tf][ks], s[nf][tf]);
    }
  }

  // s_acc = 2*(q.k); true compat = (q.k)/8 -> exp2(s_acc * log2e/16)
  const float CE2 = 0.09016844005556021f;
  u64 mq[4];
#pragma unroll
  for (int tf = 0; tf < 4; tf++)
    mq[tf] = maskbits[((long long)(b * 128) + tt0 + tf * 16 + fr) * 8 + wid];
  float psum[4] = {0.f, 0.f, 0.f, 0.f};
#pragma unroll
  for (int nf = 0; nf < 4; nf++) {
#pragma unroll
    for (int tf = 0; tf < 4; tf++) {
      float pv[4];
#pragma unroll
      for (int q = 0; q < 4; q++) {
        const int bit = nf * 16 + fq * 4 + q;
        float v = exp2f(s[nf][tf][q] * CE2);
        if ((mq[tf] >> bit) & 1ull) v = 0.0f;
        psum[tf] += v;
        pv[q] = v;
      }
      const u32 pw = pk4_fp8(pv[0], pv[1], pv[2], pv[3]);
      const int t = tf * 16 + fr;
      const int o = wstrip + nf * 16 + fq * 4;
      const int s8 = o >> 3, lo = o & 7;
      *(u32*)(Plds + t * 528 + (((s8 ^ (t & 7)) << 3) | lo)) = pw;
    }
  }
#pragma unroll
  for (int tf = 0; tf < 4; tf++) {
    float v = psum[tf];
    v += __shfl_xor(v, 16);
    v += __shfl_xor(v, 32);
    if (lane < 16) rsw[(tf * 16 + lane) * 8 + wid] = v;
  }
  __syncthreads();  // P + rsw visible; V staging drained

  if (tid < 64) {
    float sum = rsw[tid * 8];
#pragma unroll
    for (int ww = 1; ww < 8; ww++) sum += rsw[tid * 8 + ww];
    rst[tid] = __builtin_amdgcn_rcpf(sum);
  }

  const int kkh = wid & 1;
  const int tts = wid >> 1;
  f32x4 o[2];
  o[0] = (f32x4){0.f, 0.f, 0.f, 0.f};
  o[1] = (f32x4){0.f, 0.f, 0.f, 0.f};
  const int tpv = tts * 16 + fr;
#pragma unroll
  for (int nstep = 0; nstep < 16; nstep++) {
    const int s8 = nstep * 4 + fq;
    long pf = *(const long*)(Plds + tpv * 528 + ((s8 ^ (tpv & 7)) << 3));
#pragma unroll
    for (int kf = 0; kf < 2; kf++) {
      const int kk = kkh * 32 + kf * 16 + fr;
      const int vs16 = s8 >> 1, vlo = s8 & 1;
      long vf = *(const long*)(lds + kk * 512 + (((vs16 ^ (kk & 7)) << 4) | (vlo << 3)));
      o[kf] = mfma8(vf, pf, o[kf]);
    }
  }
  __syncthreads();  // rst visible

  const float r4 = rst[tpv] * 4.0f;
  const long long orow = (long long)b * 128 + tt0 + tpv;
#pragma unroll
  for (int kf = 0; kf < 2; kf++) {
    const u32 pw = pk4_fp8(o[kf][0] * r4, o[kf][1] * r4, o[kf][2] * r4, o[kf][3] * r4);
    const int col = h * 64 + kkh * 32 + kf * 16 + fq * 4;
    *(u32*)&o8buf[orow * 512 + col] = pw;
  }
}

// ---------------------------------------------------------------- launch
extern "C" void kernel_launch(void* const* d_in, const int* in_sizes, int n_in,
                              void* d_out, int out_size, void* d_ws, size_t ws_size,
                              hipStream_t stream) {
  (void)in_sizes; (void)n_in; (void)out_size; (void)ws_size;
  const float* emb  = (const float*)d_in[0];
  const int*   cur  = (const int*)d_in[1];
  const float* ucap = (const float*)d_in[2];
  const float* ubat = (const float*)d_in[3];
  const float* ctim = (const float*)d_in[4];
  const void*  mask = d_in[5];
  const float* Wc   = (const float*)d_in[6];
  const float* Wkvl = (const float*)d_in[7];
  const float* Wstep= (const float*)d_in[8];
  const float* Wout = (const float*)d_in[9];

  char* w = (char*)d_ws;
  size_t off = 0;
  auto take = [&](size_t nbytes) -> char* {
    char* p = w + off;
    off += (nbytes + 255) & ~(size_t)255;
    return p;
  };
  unsigned char* maskb = (unsigned char*)take((size_t)256 * 128 * 64);   // 2 MB
  u8* e8               = (u8*)take((size_t)256 * 512 * 512);             // 67 MB fp8 emb
  u8* WkT8             = (u8*)take((size_t)1024 * 512);                  // fp8 x16
  u8* WstepT8          = (u8*)take((size_t)512 * 576);                   // fp8 x16
  u16* W2bf            = (u16*)take((size_t)512 * 512 * 2);
  u16* Woutbf          = (u16*)take((size_t)512 * 512 * 2);
  u8* WfT8             = (u8*)take((size_t)512 * 512);                   // fp8 x64
  float* pmean         = (float*)take((size_t)1024 * 512 * 4);
  float* fixedc        = (float*)take((size_t)256 * 512 * 4);
  u8* K8               = (u8*)take((size_t)256 * 8 * 512 * 64);          // 67 MB
  u8* V8               = (u8*)take((size_t)256 * 8 * 64 * 512);          // 67 MB
  u8* nextn8           = (u8*)take((size_t)32768 * 576);                 // 18.9 MB
  u8* q8               = (u8*)take((size_t)32768 * 512);                 // 16.8 MB
  u8* o8               = (u8*)take((size_t)32768 * 512);                 // 16.8 MB
  u8* tmp8             = (u8*)take((size_t)32768 * 512);                 // 16.8 MB

  maskprep_kernel<<<8192, 256, 0, stream>>>(mask, maskb);
  tcvt8both_kernel<<<1536, 256, 0, stream>>>(Wkvl, Wstep, WkT8, WstepT8);
  wcvt_kernel<<<2048, 256, 0, stream>>>(Wkvl, Wout, W2bf, Woutbf);
  gemm128_plain_kernel<<<16, 256, 0, stream>>>(W2bf, Woutbf, WfT8);
  cvt_pmean_kernel<<<1024, 256, 0, stream>>>(emb, e8, pmean);
  fixedctx_kernel<<<256, 256, 0, stream>>>(pmean, Wc, fixedc);
  build_nextn8_kernel<<<8192, 256, 0, stream>>>(e8, cur, ucap, ubat, ctim, nextn8);

  // KV projection (fp8 datapath, coalesced epilogue)
  gemm_kv8_kernel<<<512, 512, 0, stream>>>(e8, WkT8, K8, V8);
  // q8 = fp8( 2 * (fixedc + nextn8 @ WstepT8 / 16) ), K=576, NT=9
  gemm8_kernel<0><<<512, 512, 0, stream>>>(nextn8, WstepT8, 576, 576, 9, q8, fixedc);
  // attention v5 (fp8): block = (b, h, t-half)
  attn_kernel<<<4096, 512, 0, stream>>>(q8, K8, V8, (const u64*)maskb, o8);
  // tmp8 = fp8( (o8 @ WfT8) / 32 ) = 8 * true, K=512, NT=8
  gemm8_kernel<1><<<512, 512, 0, stream>>>(o8, WfT8, 512, 512, 8, tmp8, nullptr);
  // logits (fp8 GEMM) + tanh/mask + log-softmax fused -> f32 d_out
  gemm_lsm8_kernel<<<512, 512, 0, stream>>>(e8, tmp8, (const u64*)maskb, (float*)d_out);
}